// Round 6
// baseline (2042.013 us; speedup 1.0000x reference)
//
#include <hip/hip_runtime.h>
#include <hip/hip_bf16.h>
#include <math.h>

#define N_NODES 50000
#define N_EDGES 800000
#define EMB 128
#define LH 256
#define NSENT 2048
#define MAXLEN 32
#define SCAN_NB 196   // ceil(50000/256)
#define NG 64         // sentences per group
#define NGRP 32       // groups (NSENT/NG)

typedef __attribute__((ext_vector_type(8))) short short8;
typedef __attribute__((ext_vector_type(4))) float f32x4;

__device__ __forceinline__ unsigned short f2bf_u(float f) {
    __hip_bfloat16 h = __float2bfloat16(f);
    return *reinterpret_cast<unsigned short*>(&h);
}
__device__ __forceinline__ float bfu2f(unsigned short u) {
    unsigned int x = ((unsigned int)u) << 16;
    return __uint_as_float(x);
}

// fast activations: ~1e-7 abs error, negligible vs bf16 h-state rounding (2^-9)
__device__ __forceinline__ float fsig(float x) {
    return 1.f / (1.f + __expf(-x));
}
__device__ __forceinline__ float ftanh(float x) {
    return 1.f - 2.f / (__expf(2.f * x) + 1.f);
}

#define WAITVM0() __builtin_amdgcn_s_waitcnt(0xF70)   // vmcnt(0)

// async global->LDS, 16B/lane; gsrc per-lane, LDS dst = wave-uniform base + lane*16
__device__ __forceinline__ void gload_lds16(const void* gsrc, void* ldst) {
    __builtin_amdgcn_global_load_lds(
        (const __attribute__((address_space(1))) unsigned int*)gsrc,
        (__attribute__((address_space(3))) unsigned int*)ldst, 16, 0, 0);
}

// ---------------- CSR build ----------------

__global__ void k_hist(const int* __restrict__ dst, int* __restrict__ cnt) {
    int i = blockIdx.x * 256 + threadIdx.x;
    if (i < N_EDGES) atomicAdd(&cnt[dst[i]], 1);
}

__global__ void k_scan_blk(const int* __restrict__ cnt, int* __restrict__ row_ptr,
                           int* __restrict__ blk) {
    int b = blockIdx.x, t = threadIdx.x;
    int i = b * 256 + t;
    int lane = t & 63, wid = t >> 6;
    int v = (i < N_NODES) ? cnt[i] : 0;
    int x = v;
    #pragma unroll
    for (int off = 1; off < 64; off <<= 1) {
        int y = __shfl_up(x, off);
        if (lane >= off) x += y;
    }
    __shared__ int ws[4];
    if (lane == 63) ws[wid] = x;
    __syncthreads();
    if (t == 0) {
        int s = 0;
        #pragma unroll
        for (int j = 0; j < 4; j++) { int tmp = ws[j]; ws[j] = s; s += tmp; }
        blk[b] = s;
    }
    __syncthreads();
    if (i < N_NODES) row_ptr[i] = ws[wid] + x - v;
}

__global__ void k_scan_tot(int* __restrict__ blk) {
    int t = threadIdx.x;
    int lane = t & 63, wid = t >> 6;
    int v = (t < SCAN_NB) ? blk[t] : 0;
    int x = v;
    #pragma unroll
    for (int off = 1; off < 64; off <<= 1) {
        int y = __shfl_up(x, off);
        if (lane >= off) x += y;
    }
    __shared__ int ws[4];
    if (lane == 63) ws[wid] = x;
    __syncthreads();
    if (t == 0) {
        int s = 0;
        #pragma unroll
        for (int j = 0; j < 4; j++) { int tmp = ws[j]; ws[j] = s; s += tmp; }
    }
    __syncthreads();
    if (t < SCAN_NB) blk[t] = ws[wid] + x - v;
}

__global__ void k_scan_add(int* __restrict__ row_ptr, const int* __restrict__ blk) {
    int i = blockIdx.x * 256 + threadIdx.x;
    if (i < N_NODES) row_ptr[i] += blk[i >> 8];
    if (i == 0) row_ptr[N_NODES] = N_EDGES;
}

__global__ void k_scatter(const int* __restrict__ src, const int* __restrict__ dst,
                          const int* __restrict__ row_ptr, int* __restrict__ cnt,
                          int* __restrict__ edge_src) {
    int i = blockIdx.x * 256 + threadIdx.x;
    if (i < N_EDGES) {
        int d = dst[i];
        int pos = row_ptr[d] + atomicAdd(&cnt[d], 1);
        edge_src[pos] = src[i];
    }
}

// ---------------- fp32 -> bf16 convert (inputs) ----------------

__global__ void k_tobf16(const float* __restrict__ x, unsigned short* __restrict__ y) {
    int i = blockIdx.x * 256 + threadIdx.x;
    float4 v = ((const float4*)x)[i];
    ushort4 u;
    u.x = f2bf_u(v.x); u.y = f2bf_u(v.y); u.z = f2bf_u(v.z); u.w = f2bf_u(v.w);
    ((ushort4*)y)[i] = u;
}

// ---------------- aggregation: wave per node, 4 edge-slots x 16B/lane ----------------

__global__ void k_aggregate_bf(const unsigned short* __restrict__ feat,
                               const int* __restrict__ row_ptr,
                               const int* __restrict__ edge_src,
                               unsigned short* __restrict__ outb) {
    int w = (blockIdx.x * 256 + threadIdx.x) >> 6;
    int lane = threadIdx.x & 63;
    if (w >= N_NODES) return;
    int slot = lane >> 4, li = lane & 15;
    int beg = row_ptr[w], end = row_ptr[w + 1];
    float acc[8] = {};
    #pragma unroll 1
    for (int e = beg; e < end; e += 4) {
        int eidx = e + slot;
        if (eidx < end) {
            int s = edge_src[eidx];
            short8 v = *(const short8*)((const short*)feat + (size_t)s * EMB + li * 8);
            #pragma unroll
            for (int j = 0; j < 8; j++) acc[j] += bfu2f((unsigned short)v[j]);
        }
    }
    #pragma unroll
    for (int j = 0; j < 8; j++) {
        float t = acc[j];
        t += __shfl_xor(t, 16);
        t += __shfl_xor(t, 32);
        acc[j] = t;
    }
    if (slot == 0) {
        short8 o;
        #pragma unroll
        for (int j = 0; j < 8; j++) o[j] = (short)f2bf_u(acc[j]);
        *(short8*)((short*)outb + (size_t)w * EMB + li * 8) = o;
    }
}

// ---------------- GCN linear via MFMA ----------------

__global__ void __launch_bounds__(256)
k_gcn_mfma(const unsigned short* __restrict__ Ab,   // [M][128] bf16
           const unsigned short* __restrict__ Wb,   // [128][128] bf16
           const float* __restrict__ bias,
           unsigned short* __restrict__ outb,
           int M, int do_tanh) {
    int tid = threadIdx.x;
    int w = tid >> 6, lane = tid & 63;
    int l16 = lane & 15, quad = lane >> 4;
    int rbase = blockIdx.x * 64 + w * 16;
    int arow = rbase + l16;
    if (arow >= M) arow = M - 1;
    const short* Ap = (const short*)Ab + (size_t)arow * 128 + quad * 8;
    const short* Wp = (const short*)Wb;
    f32x4 acc[8] = {};
    #pragma unroll
    for (int ks = 0; ks < 4; ks++) {
        short8 a = *(const short8*)(Ap + ks * 32);
        #pragma unroll
        for (int ct = 0; ct < 8; ct++) {
            short8 b = *(const short8*)(Wp + (size_t)(ct * 16 + l16) * 128 + ks * 32 + quad * 8);
            acc[ct] = __builtin_amdgcn_mfma_f32_16x16x32_bf16(a, b, acc[ct], 0, 0, 0);
        }
    }
    #pragma unroll
    for (int ct = 0; ct < 8; ct++) {
        float bcol = bias[ct * 16 + l16];
        #pragma unroll
        for (int r = 0; r < 4; r++) {
            int row = rbase + quad * 4 + r;
            if (row < M) {
                float v = acc[ct][r] + bcol;
                if (do_tanh) v = tanhf(v);
                outb[(size_t)row * 128 + ct * 16 + l16] = f2bf_u(v);
            }
        }
    }
}

// ---------------- prep: Wpk3 (per-u-slice fragment-linear Wi|Wh) ----------------
// Block usl (0..7) owns h-cols u in [usl*32, usl*32+32) for ALL 4 gates ->
// 128 gate rows R = g*256 + usl*32 + u' over K=384 (k<128: Wi, k>=128: Wh) = 96 KB.
// Fragment (ks 0..11, ct = g*2 + (u'>>4)) at ((usl*12+ks)*8+ct)*512 shorts; element
// lane*8+jj = W[R(ct, l16=lane&15)][ks*32 + (lane>>4)*8 + jj].

__global__ void k_prep(const float* __restrict__ Wi, const float* __restrict__ Wh,
                       const float* __restrict__ bi, const float* __restrict__ bh,
                       const float* __restrict__ W1, const float* __restrict__ W2,
                       unsigned short* __restrict__ Wpk3, float* __restrict__ bsum,
                       unsigned short* __restrict__ W1b, unsigned short* __restrict__ W2b) {
    int idx = blockIdx.x * 256 + threadIdx.x;
    if (idx < 1024 * 384) {
        int R = idx / 384, k = idx - R * 384;
        float v = (k < 128) ? Wi[R * 128 + k] : Wh[R * 256 + (k - 128)];
        int g = R >> 8, u = R & 255;
        int usl = u >> 5, up = u & 31;
        int ct = g * 2 + (up >> 4);
        int l16v = up & 15;
        int ks = k >> 5, kk = k & 31;
        int quad = kk >> 3, jj = kk & 7;
        int lane = quad * 16 + l16v;
        Wpk3[(((size_t)usl * 12 + ks) * 8 + ct) * 512 + lane * 8 + jj] = f2bf_u(v);
    } else if (idx < 1024 * 384 + 1024) {
        int r = idx - 1024 * 384;
        bsum[r] = bi[r] + bh[r];
    } else if (idx < 1024 * 384 + 1024 + 16384) {
        int r = idx - (1024 * 384 + 1024);
        W1b[r] = f2bf_u(W1[r]);
    } else if (idx < 1024 * 384 + 1024 + 32768) {
        int r = idx - (1024 * 384 + 1024 + 16384);
        W2b[r] = f2bf_u(W2[r]);
    }
}

// ---------------- LSTM: weight-stationary, atomic h-exchange, per-wave sync ----------
// R19 post-mortem (R5 = 336us, 10.5us/step ~ 25K cyc): accounted MFMA 1.5K + VALU 3.4K
// + GEMM LDS port 5.8K (480 ds_read_b128 x 12cyc) + conflicts 1.4K; rest = sync chain
// (5 barriers + tid0-spin broadcast) and x-gload drain on the critical path. Fixes:
// (1) per-wave arrive/spin: lane0 fetch_add (target 64*t) after per-wave vmcnt(0);
//     per-wave exec-masked acquire spin. Barriers 5 -> 3. The spin also fences the
//     gl<->xb/hb alias WAR: xb/hb writes for step t happen only after ALL 64 waves
//     arrived, i.e. all gl reads of t-1 are done.
// (2) x(t+1) prefetched into REGISTERS (2 x b128/thread) issued before the GEMM
//     (latency hidden under 48 MFMAs); ds_written to xb after the spin. t=0 staged
//     by prologue gload_lds; hb zeroed in LDS (t=0 reads no hX).
// (3) GEMM retiled to 32x32 wave tiles (2 m-groups x 4 col-groups): 48 instead of 60
//     ds_read_b128 per wave per step (B reads 4->2 per ks, A 1->2).

__global__ void __launch_bounds__(512)
k_lstm_ws8(const unsigned short* __restrict__ hn_bf,   // [N_NODES][128] bf16
           const unsigned short* __restrict__ Wpk3,    // packed, see k_prep
           const float* __restrict__ bsum,             // [1024]
           const int* __restrict__ sidx,               // [NSENT][MAXLEN]
           const int* __restrict__ lengths,            // [NSENT]
           unsigned long long* __restrict__ hX,        // [2][NSENT][64] (256 bf16/row)
           int* __restrict__ gcnt,                     // [NGRP*32] arrival ctrs (memset 0)
           float* __restrict__ h_last) {               // [NSENT][256] fp32
    __shared__ unsigned short wlds[12 * 8 * 512];                      // 96 KB
    __shared__ __attribute__((aligned(16))) unsigned char ubuf[49152]; // xbuf|hbuf / gbuf
    __shared__ int nid_sh[NG * 33];                                    // 8448 B

    int tid = threadIdx.x;
    int w = tid >> 6, lane = tid & 63;
    int l16 = lane & 15, quad = lane >> 4;
    int usl = blockIdx.x >> 5;        // u-slice 0..7
    int grp = blockIdx.x & 31;        // sentence group 0..31 (same-XCD under %8 rr)
    int s0 = grp * NG;
    const short* hnp = (const short*)hn_bf;

    short* xb = (short*)ubuf;                   // [64][128] bf16, chunk-swizzled
    short* hb = (short*)(ubuf + 16384);         // [64][256] bf16, chunk-swizzled
    float* gl = (float*)ubuf;                   // [64][132] f32 gates (aliases xb/hb)

    // ---- prologue: weight slice -> LDS; x0 -> xb; hb = 0; nid/len ----
    {
        const short* wsrc = (const short*)Wpk3 + (size_t)usl * 49152 + lane * 8;
        #pragma unroll
        for (int i = 0; i < 12; i++)
            gload_lds16(wsrc + (size_t)(i * 8 + w) * 512,
                        (void*)((char*)wlds + (size_t)(i * 8 + w) * 1024));
    }
    #pragma unroll
    for (int i = 0; i < 2; i++) {
        int row = w * 8 + i * 4 + quad;
        int nid = sidx[(size_t)(s0 + row) * MAXLEN + 0];
        int schunk = (l16 & ~7) | ((l16 ^ row) & 7);
        gload_lds16(hnp + (size_t)nid * 128 + schunk * 8,
                    (void*)(ubuf + (size_t)(w * 8 + i * 4) * 256));
    }
    for (int i = tid; i < NG * 32; i += 512)
        nid_sh[(i >> 5) * 33 + (i & 31)] = sidx[(size_t)(s0 + (i >> 5)) * MAXLEN + (i & 31)];
    for (int i = tid; i < 64 * 128; i += 512) ((unsigned int*)hb)[i] = 0;  // h_{-1}=0

    // pointwise-thread constants: (psent = tid>>3, 4 h-cols u'0 = (tid&7)*4 ..)
    int psent = tid >> 3, j8 = tid & 7, u0 = j8 * 4;
    float bs[4][4];
    #pragma unroll
    for (int g = 0; g < 4; g++)
        #pragma unroll
        for (int j = 0; j < 4; j++)
            bs[g][j] = bsum[g * 256 + usl * 32 + u0 + j];
    int len_reg = lengths[s0 + psent];
    float c_reg[4] = {};

    int m2 = w >> 2, cp4 = w & 3;     // GEMM wave grid: 2 m-groups x 4 col-groups (32x32)
    int row0 = m2 * 32 + l16, row1 = row0 + 16;

    short8 xr[2];                     // x(t+1) register prefetch

    __syncthreads();                  // prologue staged (drains gload vmcnt)

    #pragma unroll 1
    for (int t = 0; t < MAXLEN; t++) {
        if (t > 0) {
            // ---- per-wave acquire spin: all 64 waves of the group arrived t-1 ----
            if (lane == 0) {
                while (__hip_atomic_load(&gcnt[grp * 32], __ATOMIC_ACQUIRE,
                                         __HIP_MEMORY_SCOPE_AGENT) < 64 * t)
                    __builtin_amdgcn_s_sleep(1);
            }
            // ---- x_t: ds_write prefetched regs (gl reads of t-1 all done) ----
            {
                int row = tid >> 3;
                #pragma unroll
                for (int k = 0; k < 2; k++) {
                    int slot = j8 * 2 + k;
                    *(short8*)(xb + row * 128 + slot * 8) = xr[k];
                }
            }
            // ---- h_t: agent-scope atomic loads -> swizzled ds_write to hb ----
            {
                const unsigned long long* hr = hX + (size_t)(t & 1) * NSENT * 64
                                               + (size_t)(s0 + psent) * 64 + j8 * 8;
                unsigned long long hv[8];
                #pragma unroll
                for (int k = 0; k < 8; k++)
                    hv[k] = __hip_atomic_load(&hr[k], __ATOMIC_RELAXED,
                                              __HIP_MEMORY_SCOPE_AGENT);
                #pragma unroll
                for (int p = 0; p < 4; p++) {
                    int cc = j8 * 4 + p;
                    int slot = (cc & ~7) | ((cc ^ psent) & 7);
                    union { unsigned long long q[2]; short8 s; } uu;
                    uu.q[0] = hv[2 * p]; uu.q[1] = hv[2 * p + 1];
                    *(short8*)(hb + psent * 256 + slot * 8) = uu.s;
                }
            }
            __syncthreads();   // B1: staging visible to all waves
        }

        // ---- issue x(t+1) global->reg prefetch (hidden under GEMM) ----
        if (t + 1 < MAXLEN) {
            int row = tid >> 3;
            int nid = nid_sh[row * 33 + (t + 1)];
            #pragma unroll
            for (int k = 0; k < 2; k++) {
                int slot = j8 * 2 + k;
                int c = (slot & ~7) | ((slot ^ row) & 7);
                xr[k] = *(const short8*)(hnp + (size_t)nid * 128 + c * 8);
            }
        }

        // ---- GEMM: wave = rows [m2*32, +32) x cols [cp4*32, +32), K=384 ----
        f32x4 acc00 = {}, acc01 = {}, acc10 = {}, acc11 = {};
        #pragma unroll
        for (int ks = 0; ks < 12; ks++) {
            short8 a0, a1;
            if (ks < 4) {
                int kc = ks * 4 + quad;
                a0 = *(const short8*)(xb + row0 * 128 + (((kc & ~7) | ((kc ^ row0) & 7)) * 8));
                a1 = *(const short8*)(xb + row1 * 128 + (((kc & ~7) | ((kc ^ row1) & 7)) * 8));
            } else {
                int kc = (ks - 4) * 4 + quad;
                a0 = *(const short8*)(hb + row0 * 256 + (((kc & ~7) | ((kc ^ row0) & 7)) * 8));
                a1 = *(const short8*)(hb + row1 * 256 + (((kc & ~7) | ((kc ^ row1) & 7)) * 8));
            }
            const short* bbase = (const short*)wlds + (size_t)(ks * 8 + cp4 * 2) * 512 + lane * 8;
            short8 b0 = *(const short8*)(bbase);
            short8 b1 = *(const short8*)(bbase + 512);
            acc00 = __builtin_amdgcn_mfma_f32_16x16x32_bf16(a0, b0, acc00, 0, 0, 0);
            acc01 = __builtin_amdgcn_mfma_f32_16x16x32_bf16(a0, b1, acc01, 0, 0, 0);
            acc10 = __builtin_amdgcn_mfma_f32_16x16x32_bf16(a1, b0, acc10, 0, 0, 0);
            acc11 = __builtin_amdgcn_mfma_f32_16x16x32_bf16(a1, b1, acc11, 0, 0, 0);
        }
        __syncthreads();   // B2: xb/hb reads done -> safe to alias as gl

        // ---- acc -> gates f32 [64][132] (ncol = ct*16+l16 = g*32+u') ----
        #pragma unroll
        for (int r = 0; r < 4; r++) {
            int se0 = m2 * 32 + quad * 4 + r;
            int se1 = se0 + 16;
            gl[se0 * 132 + cp4 * 32 + l16]      = acc00[r];
            gl[se0 * 132 + cp4 * 32 + 16 + l16] = acc01[r];
            gl[se1 * 132 + cp4 * 32 + l16]      = acc10[r];
            gl[se1 * 132 + cp4 * 32 + 16 + l16] = acc11[r];
        }
        __syncthreads();   // B3: gates ready

        // ---- pointwise c/h for (psent, u-cols usl*32+u0 .. +3) ----
        {
            float4 G[4];
            #pragma unroll
            for (int g = 0; g < 4; g++)
                G[g] = *(const float4*)&gl[psent * 132 + g * 32 + u0];
            float hv4[4];
            const float* Gp0 = (const float*)&G[0];
            const float* Gp1 = (const float*)&G[1];
            const float* Gp2 = (const float*)&G[2];
            const float* Gp3 = (const float*)&G[3];
            #pragma unroll
            for (int j = 0; j < 4; j++) {
                float i_ = fsig(Gp0[j] + bs[0][j]);
                float f_ = fsig(Gp1[j] + bs[1][j]);
                float g_ = ftanh(Gp2[j] + bs[2][j]);
                float o_ = fsig(Gp3[j] + bs[3][j]);
                float c = f_ * c_reg[j] + i_ * g_;
                c_reg[j] = c;
                hv4[j] = o_ * ftanh(c);
            }
            unsigned long long hq =
                  (unsigned long long)f2bf_u(hv4[0])
                | ((unsigned long long)f2bf_u(hv4[1]) << 16)
                | ((unsigned long long)f2bf_u(hv4[2]) << 32)
                | ((unsigned long long)f2bf_u(hv4[3]) << 48);
            unsigned long long* hw = hX + (size_t)((t + 1) & 1) * NSENT * 64
                                     + (size_t)(s0 + psent) * 64 + usl * 8 + j8;
            __hip_atomic_store(hw, hq, __ATOMIC_RELAXED, __HIP_MEMORY_SCOPE_AGENT);
            if (len_reg == t + 1) {
                float4 o4 = make_float4(hv4[0], hv4[1], hv4[2], hv4[3]);
                *(float4*)&h_last[(size_t)(s0 + psent) * 256 + usl * 32 + u0] = o4;
            }
        }

        // ---- per-wave arrive: own stores ack'd at coherence point, release add ----
        if (t + 1 < MAXLEN) {
            WAITVM0();
            if (lane == 0)
                __hip_atomic_fetch_add(&gcnt[grp * 32], 1, __ATOMIC_RELEASE,
                                       __HIP_MEMORY_SCOPE_AGENT);
        }
    }
}

// ---------------- classifier ----------------

__global__ void k_classifier(const float* __restrict__ h_last,
                             const float* __restrict__ Wc1, const float* __restrict__ bc1,
                             const float* __restrict__ Wc2, const float* __restrict__ bc2,
                             float* __restrict__ out) {
    int lane = threadIdx.x & 63;
    int wslot = threadIdx.x >> 6;
    int s = blockIdx.x * 4 + wslot;
    __shared__ float e_sh[4][256];
    const float* hr = h_last + (size_t)s * 256;
    #pragma unroll
    for (int i = 0; i < 4; i++) {
        float v = hr[lane + 64 * i];
        e_sh[wslot][lane + 64 * i] = fmaxf(v, 0.f);
    }
    __syncthreads();
    float zpart = 0.f;
    #pragma unroll
    for (int jj = 0; jj < 2; jj++) {
        int j = lane + 64 * jj;
        float a = bc1[j];
        const float4* wr = (const float4*)(Wc1 + (size_t)j * 256);
        #pragma unroll 8
        for (int k4 = 0; k4 < 64; k4++) {
            float4 wv = wr[k4];
            float4 e = *(const float4*)&e_sh[wslot][k4 * 4];
            a += wv.x * e.x + wv.y * e.y + wv.z * e.z + wv.w * e.w;
        }
        a = fmaxf(a, 0.f);
        zpart += a * Wc2[j];
    }
    #pragma unroll
    for (int off = 32; off > 0; off >>= 1) zpart += __shfl_down(zpart, off);
    if (lane == 0) out[s] = zpart + bc2[0];
}

// ---------------- launcher ----------------

extern "C" void kernel_launch(void* const* d_in, const int* in_sizes, int n_in,
                              void* d_out, int out_size, void* d_ws, size_t ws_size,
                              hipStream_t stream) {
    const float* inputs = (const float*)d_in[0];
    const float* W1  = (const float*)d_in[1];
    const float* b1  = (const float*)d_in[2];
    const float* W2  = (const float*)d_in[3];
    const float* b2  = (const float*)d_in[4];
    const float* Wi  = (const float*)d_in[5];
    const float* Wh  = (const float*)d_in[6];
    const float* bi  = (const float*)d_in[7];
    const float* bh  = (const float*)d_in[8];
    const float* Wc1 = (const float*)d_in[9];
    const float* bc1 = (const float*)d_in[10];
    const float* Wc2 = (const float*)d_in[11];
    const float* bc2 = (const float*)d_in[12];
    const int* src      = (const int*)d_in[13];
    const int* dst      = (const int*)d_in[14];
    const int* sidx     = (const int*)d_in[15];
    const int* lengths  = (const int*)d_in[16];
    float* out = (float*)d_out;

    char* ws = (char*)d_ws;
    size_t off = 0;
    auto alloc = [&](size_t bytes) -> void* {
        void* p = ws + off;
        off = (off + bytes + 255) & ~(size_t)255;
        return p;
    };
    unsigned short* in_bf  = (unsigned short*)alloc(2 * (size_t)N_NODES * EMB);
    unsigned short* agg_bf = (unsigned short*)alloc(2 * (size_t)N_NODES * EMB);
    unsigned short* h_bf   = (unsigned short*)alloc(2 * (size_t)N_NODES * EMB);
    unsigned short* hn_bf  = (unsigned short*)alloc(2 * (size_t)N_NODES * EMB);
    int*   row_ptr  = (int*)alloc(sizeof(int) * (N_NODES + 1));
    int*   cnt      = (int*)alloc(sizeof(int) * N_NODES);
    int*   blk      = (int*)alloc(sizeof(int) * SCAN_NB);
    int*   edge_src = (int*)alloc(sizeof(int) * N_EDGES);
    unsigned short* Wpk3 = (unsigned short*)alloc(2 * 8 * 12 * 8 * 512);  // 768 KB
    unsigned short* W1b  = (unsigned short*)alloc(2 * 128 * 128);
    unsigned short* W2b  = (unsigned short*)alloc(2 * 128 * 128);
    float* bsum     = (float*)alloc(sizeof(float) * 1024);
    float* hlast    = (float*)alloc(sizeof(float) * NSENT * LH);
    unsigned long long* hX = (unsigned long long*)alloc(2 * (size_t)NSENT * 64 * 8);  // 2 MB
    int* gcnt       = (int*)alloc(sizeof(int) * NGRP * 32);

    // weight prep (independent of everything else)
    k_prep<<<(1024 * 384 + 1024 + 32768 + 255) / 256, 256, 0, stream>>>(
        Wi, Wh, bi, bh, W1, W2, Wpk3, bsum, W1b, W2b);

    // LSTM exchange buffers: arrival counters = 0 (hX zeroed for hygiene)
    hipMemsetAsync(hX, 0, 2 * (size_t)NSENT * 64 * 8, stream);
    hipMemsetAsync(gcnt, 0, sizeof(int) * NGRP * 32, stream);

    // CSR build
    hipMemsetAsync(cnt, 0, sizeof(int) * N_NODES, stream);
    k_hist<<<(N_EDGES + 255) / 256, 256, 0, stream>>>(dst, cnt);
    k_scan_blk<<<SCAN_NB, 256, 0, stream>>>(cnt, row_ptr, blk);
    k_scan_tot<<<1, 256, 0, stream>>>(blk);
    k_scan_add<<<SCAN_NB, 256, 0, stream>>>(row_ptr, blk);
    hipMemsetAsync(cnt, 0, sizeof(int) * N_NODES, stream);
    k_scatter<<<(N_EDGES + 255) / 256, 256, 0, stream>>>(src, dst, row_ptr, cnt, edge_src);

    // GCN (bf16 path)
    k_tobf16<<<(N_NODES * EMB / 4 + 255) / 256, 256, 0, stream>>>(inputs, in_bf);
    k_aggregate_bf<<<(N_NODES * 64) / 256, 256, 0, stream>>>(in_bf, row_ptr, edge_src, agg_bf);
    k_gcn_mfma<<<(N_NODES + 63) / 64, 256, 0, stream>>>(agg_bf, W1b, b1, h_bf, N_NODES, 1);
    k_aggregate_bf<<<(N_NODES * 64) / 256, 256, 0, stream>>>(h_bf, row_ptr, edge_src, agg_bf);
    k_gcn_mfma<<<(N_NODES + 63) / 64, 256, 0, stream>>>(agg_bf, W2b, b2, hn_bf, N_NODES, 0);

    // LSTM: weight-stationary, 256 blocks = 8 u-slices x 32 groups, per-wave sync
    k_lstm_ws8<<<NGRP * 8, 512, 0, stream>>>(hn_bf, Wpk3, bsum, sidx, lengths,
                                             hX, gcnt, hlast);

    // classifier
    k_classifier<<<NSENT / 4, 256, 0, stream>>>(hlast, Wc1, bc1, Wc2, bc2, out);
}

// Round 7
// 654.433 us; speedup vs baseline: 3.1203x; 3.1203x over previous
//
#include <hip/hip_runtime.h>
#include <hip/hip_bf16.h>
#include <math.h>

#define N_NODES 50000
#define N_EDGES 800000
#define EMB 128
#define LH 256
#define NSENT 2048
#define MAXLEN 32
#define SCAN_NB 196   // ceil(50000/256)
#define NG 64         // sentences per group
#define NGRP 32       // groups (NSENT/NG)

typedef __attribute__((ext_vector_type(8))) short short8;
typedef __attribute__((ext_vector_type(4))) float f32x4;

__device__ __forceinline__ unsigned short f2bf_u(float f) {
    __hip_bfloat16 h = __float2bfloat16(f);
    return *reinterpret_cast<unsigned short*>(&h);
}
__device__ __forceinline__ float bfu2f(unsigned short u) {
    unsigned int x = ((unsigned int)u) << 16;
    return __uint_as_float(x);
}

// fast activations: ~1e-7 abs error, negligible vs bf16 h-state rounding (2^-9)
__device__ __forceinline__ float fsig(float x) {
    return 1.f / (1.f + __expf(-x));
}
__device__ __forceinline__ float ftanh(float x) {
    return 1.f - 2.f / (__expf(2.f * x) + 1.f);
}

#define WAITVM0() __builtin_amdgcn_s_waitcnt(0xF70)   // vmcnt(0)

// async global->LDS, 16B/lane; gsrc per-lane, LDS dst = wave-uniform base + lane*16
__device__ __forceinline__ void gload_lds16(const void* gsrc, void* ldst) {
    __builtin_amdgcn_global_load_lds(
        (const __attribute__((address_space(1))) unsigned int*)gsrc,
        (__attribute__((address_space(3))) unsigned int*)ldst, 16, 0, 0);
}

// ---------------- CSR build ----------------

__global__ void k_hist(const int* __restrict__ dst, int* __restrict__ cnt) {
    int i = blockIdx.x * 256 + threadIdx.x;
    if (i < N_EDGES) atomicAdd(&cnt[dst[i]], 1);
}

__global__ void k_scan_blk(const int* __restrict__ cnt, int* __restrict__ row_ptr,
                           int* __restrict__ blk) {
    int b = blockIdx.x, t = threadIdx.x;
    int i = b * 256 + t;
    int lane = t & 63, wid = t >> 6;
    int v = (i < N_NODES) ? cnt[i] : 0;
    int x = v;
    #pragma unroll
    for (int off = 1; off < 64; off <<= 1) {
        int y = __shfl_up(x, off);
        if (lane >= off) x += y;
    }
    __shared__ int ws[4];
    if (lane == 63) ws[wid] = x;
    __syncthreads();
    if (t == 0) {
        int s = 0;
        #pragma unroll
        for (int j = 0; j < 4; j++) { int tmp = ws[j]; ws[j] = s; s += tmp; }
        blk[b] = s;
    }
    __syncthreads();
    if (i < N_NODES) row_ptr[i] = ws[wid] + x - v;
}

__global__ void k_scan_tot(int* __restrict__ blk) {
    int t = threadIdx.x;
    int lane = t & 63, wid = t >> 6;
    int v = (t < SCAN_NB) ? blk[t] : 0;
    int x = v;
    #pragma unroll
    for (int off = 1; off < 64; off <<= 1) {
        int y = __shfl_up(x, off);
        if (lane >= off) x += y;
    }
    __shared__ int ws[4];
    if (lane == 63) ws[wid] = x;
    __syncthreads();
    if (t == 0) {
        int s = 0;
        #pragma unroll
        for (int j = 0; j < 4; j++) { int tmp = ws[j]; ws[j] = s; s += tmp; }
    }
    __syncthreads();
    if (t < SCAN_NB) blk[t] = ws[wid] + x - v;
}

__global__ void k_scan_add(int* __restrict__ row_ptr, const int* __restrict__ blk) {
    int i = blockIdx.x * 256 + threadIdx.x;
    if (i < N_NODES) row_ptr[i] += blk[i >> 8];
    if (i == 0) row_ptr[N_NODES] = N_EDGES;
}

__global__ void k_scatter(const int* __restrict__ src, const int* __restrict__ dst,
                          const int* __restrict__ row_ptr, int* __restrict__ cnt,
                          int* __restrict__ edge_src) {
    int i = blockIdx.x * 256 + threadIdx.x;
    if (i < N_EDGES) {
        int d = dst[i];
        int pos = row_ptr[d] + atomicAdd(&cnt[d], 1);
        edge_src[pos] = src[i];
    }
}

// ---------------- fp32 -> bf16 convert (inputs) ----------------

__global__ void k_tobf16(const float* __restrict__ x, unsigned short* __restrict__ y) {
    int i = blockIdx.x * 256 + threadIdx.x;
    float4 v = ((const float4*)x)[i];
    ushort4 u;
    u.x = f2bf_u(v.x); u.y = f2bf_u(v.y); u.z = f2bf_u(v.z); u.w = f2bf_u(v.w);
    ((ushort4*)y)[i] = u;
}

// ---------------- aggregation: wave per node, 4 edge-slots x 16B/lane ----------------

__global__ void k_aggregate_bf(const unsigned short* __restrict__ feat,
                               const int* __restrict__ row_ptr,
                               const int* __restrict__ edge_src,
                               unsigned short* __restrict__ outb) {
    int w = (blockIdx.x * 256 + threadIdx.x) >> 6;
    int lane = threadIdx.x & 63;
    if (w >= N_NODES) return;
    int slot = lane >> 4, li = lane & 15;
    int beg = row_ptr[w], end = row_ptr[w + 1];
    float acc[8] = {};
    #pragma unroll 1
    for (int e = beg; e < end; e += 4) {
        int eidx = e + slot;
        if (eidx < end) {
            int s = edge_src[eidx];
            short8 v = *(const short8*)((const short*)feat + (size_t)s * EMB + li * 8);
            #pragma unroll
            for (int j = 0; j < 8; j++) acc[j] += bfu2f((unsigned short)v[j]);
        }
    }
    #pragma unroll
    for (int j = 0; j < 8; j++) {
        float t = acc[j];
        t += __shfl_xor(t, 16);
        t += __shfl_xor(t, 32);
        acc[j] = t;
    }
    if (slot == 0) {
        short8 o;
        #pragma unroll
        for (int j = 0; j < 8; j++) o[j] = (short)f2bf_u(acc[j]);
        *(short8*)((short*)outb + (size_t)w * EMB + li * 8) = o;
    }
}

// ---------------- GCN linear via MFMA ----------------

__global__ void __launch_bounds__(256)
k_gcn_mfma(const unsigned short* __restrict__ Ab,   // [M][128] bf16
           const unsigned short* __restrict__ Wb,   // [128][128] bf16
           const float* __restrict__ bias,
           unsigned short* __restrict__ outb,
           int M, int do_tanh) {
    int tid = threadIdx.x;
    int w = tid >> 6, lane = tid & 63;
    int l16 = lane & 15, quad = lane >> 4;
    int rbase = blockIdx.x * 64 + w * 16;
    int arow = rbase + l16;
    if (arow >= M) arow = M - 1;
    const short* Ap = (const short*)Ab + (size_t)arow * 128 + quad * 8;
    const short* Wp = (const short*)Wb;
    f32x4 acc[8] = {};
    #pragma unroll
    for (int ks = 0; ks < 4; ks++) {
        short8 a = *(const short8*)(Ap + ks * 32);
        #pragma unroll
        for (int ct = 0; ct < 8; ct++) {
            short8 b = *(const short8*)(Wp + (size_t)(ct * 16 + l16) * 128 + ks * 32 + quad * 8);
            acc[ct] = __builtin_amdgcn_mfma_f32_16x16x32_bf16(a, b, acc[ct], 0, 0, 0);
        }
    }
    #pragma unroll
    for (int ct = 0; ct < 8; ct++) {
        float bcol = bias[ct * 16 + l16];
        #pragma unroll
        for (int r = 0; r < 4; r++) {
            int row = rbase + quad * 4 + r;
            if (row < M) {
                float v = acc[ct][r] + bcol;
                if (do_tanh) v = tanhf(v);
                outb[(size_t)row * 128 + ct * 16 + l16] = f2bf_u(v);
            }
        }
    }
}

// ---------------- prep: Wpk3 (per-u-slice fragment-linear Wi|Wh) ----------------
// Block usl (0..7) owns h-cols u in [usl*32, usl*32+32) for ALL 4 gates ->
// 128 gate rows R = g*256 + usl*32 + u' over K=384 (k<128: Wi, k>=128: Wh) = 96 KB.
// Fragment (ks 0..11, ct = g*2 + (u'>>4)) at ((usl*12+ks)*8+ct)*512 shorts; element
// lane*8+jj = W[R(ct, l16=lane&15)][ks*32 + (lane>>4)*8 + jj].

__global__ void k_prep(const float* __restrict__ Wi, const float* __restrict__ Wh,
                       const float* __restrict__ bi, const float* __restrict__ bh,
                       const float* __restrict__ W1, const float* __restrict__ W2,
                       unsigned short* __restrict__ Wpk3, float* __restrict__ bsum,
                       unsigned short* __restrict__ W1b, unsigned short* __restrict__ W2b) {
    int idx = blockIdx.x * 256 + threadIdx.x;
    if (idx < 1024 * 384) {
        int R = idx / 384, k = idx - R * 384;
        float v = (k < 128) ? Wi[R * 128 + k] : Wh[R * 256 + (k - 128)];
        int g = R >> 8, u = R & 255;
        int usl = u >> 5, up = u & 31;
        int ct = g * 2 + (up >> 4);
        int l16v = up & 15;
        int ks = k >> 5, kk = k & 31;
        int quad = kk >> 3, jj = kk & 7;
        int lane = quad * 16 + l16v;
        Wpk3[(((size_t)usl * 12 + ks) * 8 + ct) * 512 + lane * 8 + jj] = f2bf_u(v);
    } else if (idx < 1024 * 384 + 1024) {
        int r = idx - 1024 * 384;
        bsum[r] = bi[r] + bh[r];
    } else if (idx < 1024 * 384 + 1024 + 16384) {
        int r = idx - (1024 * 384 + 1024);
        W1b[r] = f2bf_u(W1[r]);
    } else if (idx < 1024 * 384 + 1024 + 32768) {
        int r = idx - (1024 * 384 + 1024 + 16384);
        W2b[r] = f2bf_u(W2[r]);
    }
}

// ---------------- LSTM: weight-stationary, atomic h-exchange (R5 sync skeleton) -------
// R20 post-mortem: R6's per-wave arrive/spin (64 agent-scope releases + 64 spinners
// per group-step, vs R5's 8+8) multiplied agent-scope release/acquire coherence ops
// 8x -> 336 -> 1734us, all pipes idle. REVERTED to R5's proven block-level sync:
// tid0-only acquire spin (target 8t) + barrier broadcast; block-wide vmcnt(0) +
// barrier + single tid0 release. KEPT from R6 (functionally proven, buried by sync):
// (a) 32x32 GEMM wave tiles (2 m-groups x 4 col-groups): 48 instead of 60
//     ds_read_b128 per wave per step; B reads are contiguous 1KB wave-loads.
// (b) x(t+1) prefetched into REGISTERS during the GEMM (2 x b128/thread), ds_written
//     to xb after the next spin+barrier (WAR on gl alias safe: all gl reads of t-1
//     complete before any block arrives t-1). t=0 staged by prologue gload_lds;
//     hb zeroed in LDS (t=0 reads no hX).

__global__ void __launch_bounds__(512)
k_lstm_ws8(const unsigned short* __restrict__ hn_bf,   // [N_NODES][128] bf16
           const unsigned short* __restrict__ Wpk3,    // packed, see k_prep
           const float* __restrict__ bsum,             // [1024]
           const int* __restrict__ sidx,               // [NSENT][MAXLEN]
           const int* __restrict__ lengths,            // [NSENT]
           unsigned long long* __restrict__ hX,        // [2][NSENT][64] (256 bf16/row)
           int* __restrict__ gcnt,                     // [NGRP*32] arrival ctrs (memset 0)
           float* __restrict__ h_last) {               // [NSENT][256] fp32
    __shared__ unsigned short wlds[12 * 8 * 512];                      // 96 KB
    __shared__ __attribute__((aligned(16))) unsigned char ubuf[49152]; // xbuf|hbuf / gbuf
    __shared__ int nid_sh[NG * 33];                                    // 8448 B

    int tid = threadIdx.x;
    int w = tid >> 6, lane = tid & 63;
    int l16 = lane & 15, quad = lane >> 4;
    int usl = blockIdx.x >> 5;        // u-slice 0..7
    int grp = blockIdx.x & 31;        // sentence group 0..31 (same-XCD under %8 rr)
    int s0 = grp * NG;
    const short* hnp = (const short*)hn_bf;

    short* xb = (short*)ubuf;                   // [64][128] bf16, chunk-swizzled
    short* hb = (short*)(ubuf + 16384);         // [64][256] bf16, chunk-swizzled
    float* gl = (float*)ubuf;                   // [64][132] f32 gates (aliases xb/hb)

    // ---- prologue: weight slice -> LDS; x0 -> xb; hb = 0; nid table ----
    {
        const short* wsrc = (const short*)Wpk3 + (size_t)usl * 49152 + lane * 8;
        #pragma unroll
        for (int i = 0; i < 12; i++)
            gload_lds16(wsrc + (size_t)(i * 8 + w) * 512,
                        (void*)((char*)wlds + (size_t)(i * 8 + w) * 1024));
    }
    #pragma unroll
    for (int i = 0; i < 2; i++) {
        int row = w * 8 + i * 4 + quad;
        int nid = sidx[(size_t)(s0 + row) * MAXLEN + 0];
        int schunk = (l16 & ~7) | ((l16 ^ row) & 7);
        gload_lds16(hnp + (size_t)nid * 128 + schunk * 8,
                    (void*)(ubuf + (size_t)(w * 8 + i * 4) * 256));
    }
    for (int i = tid; i < NG * 32; i += 512)
        nid_sh[(i >> 5) * 33 + (i & 31)] = sidx[(size_t)(s0 + (i >> 5)) * MAXLEN + (i & 31)];
    for (int i = tid; i < 64 * 128; i += 512) ((unsigned int*)hb)[i] = 0;  // h_{-1}=0

    // pointwise-thread constants: (psent = tid>>3, 4 h-cols u'0 = (tid&7)*4 ..)
    int psent = tid >> 3, j8 = tid & 7, u0 = j8 * 4;
    float bs[4][4];
    #pragma unroll
    for (int g = 0; g < 4; g++)
        #pragma unroll
        for (int j = 0; j < 4; j++)
            bs[g][j] = bsum[g * 256 + usl * 32 + u0 + j];
    int len_reg = lengths[s0 + psent];
    float c_reg[4] = {};

    int m2 = w >> 2, cp4 = w & 3;     // GEMM wave grid: 2 m-groups x 4 col-groups (32x32)
    int row0 = m2 * 32 + l16, row1 = row0 + 16;

    short8 xr[2];                     // x(t+1) register prefetch

    __syncthreads();                  // prologue staged (drains gload vmcnt)

    #pragma unroll 1
    for (int t = 0; t < MAXLEN; t++) {
        if (t > 0) {
            // ---- B0: tid0 acquire spin (all 8 blocks of group arrived t-1) ----
            if (tid == 0) {
                while (__hip_atomic_load(&gcnt[grp * 32], __ATOMIC_ACQUIRE,
                                         __HIP_MEMORY_SCOPE_AGENT) < 8 * t)
                    __builtin_amdgcn_s_sleep(1);
            }
            __syncthreads();
            // ---- x_t: ds_write prefetched regs (gl reads of t-1 all done) ----
            {
                int row = tid >> 3;
                #pragma unroll
                for (int k = 0; k < 2; k++) {
                    int slot = j8 * 2 + k;
                    *(short8*)(xb + row * 128 + slot * 8) = xr[k];
                }
            }
            // ---- h_t: agent-scope atomic loads -> swizzled ds_write to hb ----
            {
                const unsigned long long* hr = hX + (size_t)(t & 1) * NSENT * 64
                                               + (size_t)(s0 + psent) * 64 + j8 * 8;
                unsigned long long hv[8];
                #pragma unroll
                for (int k = 0; k < 8; k++)
                    hv[k] = __hip_atomic_load(&hr[k], __ATOMIC_RELAXED,
                                              __HIP_MEMORY_SCOPE_AGENT);
                #pragma unroll
                for (int p = 0; p < 4; p++) {
                    int cc = j8 * 4 + p;
                    int slot = (cc & ~7) | ((cc ^ psent) & 7);
                    union { unsigned long long q[2]; short8 s; } uu;
                    uu.q[0] = hv[2 * p]; uu.q[1] = hv[2 * p + 1];
                    *(short8*)(hb + psent * 256 + slot * 8) = uu.s;
                }
            }
            __syncthreads();   // B1: staging visible to all waves
        }

        // ---- issue x(t+1) global->reg prefetch (hidden under GEMM) ----
        if (t + 1 < MAXLEN) {
            int row = tid >> 3;
            int nid = nid_sh[row * 33 + (t + 1)];
            #pragma unroll
            for (int k = 0; k < 2; k++) {
                int slot = j8 * 2 + k;
                int c = (slot & ~7) | ((slot ^ row) & 7);
                xr[k] = *(const short8*)(hnp + (size_t)nid * 128 + c * 8);
            }
        }

        // ---- GEMM: wave = rows [m2*32, +32) x cols [cp4*32, +32), K=384 ----
        f32x4 acc00 = {}, acc01 = {}, acc10 = {}, acc11 = {};
        #pragma unroll
        for (int ks = 0; ks < 12; ks++) {
            short8 a0, a1;
            if (ks < 4) {
                int kc = ks * 4 + quad;
                a0 = *(const short8*)(xb + row0 * 128 + (((kc & ~7) | ((kc ^ row0) & 7)) * 8));
                a1 = *(const short8*)(xb + row1 * 128 + (((kc & ~7) | ((kc ^ row1) & 7)) * 8));
            } else {
                int kc = (ks - 4) * 4 + quad;
                a0 = *(const short8*)(hb + row0 * 256 + (((kc & ~7) | ((kc ^ row0) & 7)) * 8));
                a1 = *(const short8*)(hb + row1 * 256 + (((kc & ~7) | ((kc ^ row1) & 7)) * 8));
            }
            const short* bbase = (const short*)wlds + (size_t)(ks * 8 + cp4 * 2) * 512 + lane * 8;
            short8 b0 = *(const short8*)(bbase);
            short8 b1 = *(const short8*)(bbase + 512);
            acc00 = __builtin_amdgcn_mfma_f32_16x16x32_bf16(a0, b0, acc00, 0, 0, 0);
            acc01 = __builtin_amdgcn_mfma_f32_16x16x32_bf16(a0, b1, acc01, 0, 0, 0);
            acc10 = __builtin_amdgcn_mfma_f32_16x16x32_bf16(a1, b0, acc10, 0, 0, 0);
            acc11 = __builtin_amdgcn_mfma_f32_16x16x32_bf16(a1, b1, acc11, 0, 0, 0);
        }
        __syncthreads();   // B2: xb/hb reads done -> safe to alias as gl

        // ---- acc -> gates f32 [64][132] (ncol = g*32+u', g = cp4) ----
        #pragma unroll
        for (int r = 0; r < 4; r++) {
            int se0 = m2 * 32 + quad * 4 + r;
            int se1 = se0 + 16;
            gl[se0 * 132 + cp4 * 32 + l16]      = acc00[r];
            gl[se0 * 132 + cp4 * 32 + 16 + l16] = acc01[r];
            gl[se1 * 132 + cp4 * 32 + l16]      = acc10[r];
            gl[se1 * 132 + cp4 * 32 + 16 + l16] = acc11[r];
        }
        __syncthreads();   // B3: gates ready

        // ---- pointwise c/h for (psent, u-cols usl*32+u0 .. +3) ----
        {
            float4 G[4];
            #pragma unroll
            for (int g = 0; g < 4; g++)
                G[g] = *(const float4*)&gl[psent * 132 + g * 32 + u0];
            float hv4[4];
            const float* Gp0 = (const float*)&G[0];
            const float* Gp1 = (const float*)&G[1];
            const float* Gp2 = (const float*)&G[2];
            const float* Gp3 = (const float*)&G[3];
            #pragma unroll
            for (int j = 0; j < 4; j++) {
                float i_ = fsig(Gp0[j] + bs[0][j]);
                float f_ = fsig(Gp1[j] + bs[1][j]);
                float g_ = ftanh(Gp2[j] + bs[2][j]);
                float o_ = fsig(Gp3[j] + bs[3][j]);
                float c = f_ * c_reg[j] + i_ * g_;
                c_reg[j] = c;
                hv4[j] = o_ * ftanh(c);
            }
            unsigned long long hq =
                  (unsigned long long)f2bf_u(hv4[0])
                | ((unsigned long long)f2bf_u(hv4[1]) << 16)
                | ((unsigned long long)f2bf_u(hv4[2]) << 32)
                | ((unsigned long long)f2bf_u(hv4[3]) << 48);
            unsigned long long* hw = hX + (size_t)((t + 1) & 1) * NSENT * 64
                                     + (size_t)(s0 + psent) * 64 + usl * 8 + j8;
            __hip_atomic_store(hw, hq, __ATOMIC_RELAXED, __HIP_MEMORY_SCOPE_AGENT);
            if (len_reg == t + 1) {
                float4 o4 = make_float4(hv4[0], hv4[1], hv4[2], hv4[3]);
                *(float4*)&h_last[(size_t)(s0 + psent) * 256 + usl * 32 + u0] = o4;
            }
        }

        // ---- B4 + arrive: all block stores ack'd, single release add ----
        if (t + 1 < MAXLEN) {
            WAITVM0();
            __syncthreads();
            if (tid == 0)
                __hip_atomic_fetch_add(&gcnt[grp * 32], 1, __ATOMIC_RELEASE,
                                       __HIP_MEMORY_SCOPE_AGENT);
        }
    }
}

// ---------------- classifier ----------------

__global__ void k_classifier(const float* __restrict__ h_last,
                             const float* __restrict__ Wc1, const float* __restrict__ bc1,
                             const float* __restrict__ Wc2, const float* __restrict__ bc2,
                             float* __restrict__ out) {
    int lane = threadIdx.x & 63;
    int wslot = threadIdx.x >> 6;
    int s = blockIdx.x * 4 + wslot;
    __shared__ float e_sh[4][256];
    const float* hr = h_last + (size_t)s * 256;
    #pragma unroll
    for (int i = 0; i < 4; i++) {
        float v = hr[lane + 64 * i];
        e_sh[wslot][lane + 64 * i] = fmaxf(v, 0.f);
    }
    __syncthreads();
    float zpart = 0.f;
    #pragma unroll
    for (int jj = 0; jj < 2; jj++) {
        int j = lane + 64 * jj;
        float a = bc1[j];
        const float4* wr = (const float4*)(Wc1 + (size_t)j * 256);
        #pragma unroll 8
        for (int k4 = 0; k4 < 64; k4++) {
            float4 wv = wr[k4];
            float4 e = *(const float4*)&e_sh[wslot][k4 * 4];
            a += wv.x * e.x + wv.y * e.y + wv.z * e.z + wv.w * e.w;
        }
        a = fmaxf(a, 0.f);
        zpart += a * Wc2[j];
    }
    #pragma unroll
    for (int off = 32; off > 0; off >>= 1) zpart += __shfl_down(zpart, off);
    if (lane == 0) out[s] = zpart + bc2[0];
}

// ---------------- launcher ----------------

extern "C" void kernel_launch(void* const* d_in, const int* in_sizes, int n_in,
                              void* d_out, int out_size, void* d_ws, size_t ws_size,
                              hipStream_t stream) {
    const float* inputs = (const float*)d_in[0];
    const float* W1  = (const float*)d_in[1];
    const float* b1  = (const float*)d_in[2];
    const float* W2  = (const float*)d_in[3];
    const float* b2  = (const float*)d_in[4];
    const float* Wi  = (const float*)d_in[5];
    const float* Wh  = (const float*)d_in[6];
    const float* bi  = (const float*)d_in[7];
    const float* bh  = (const float*)d_in[8];
    const float* Wc1 = (const float*)d_in[9];
    const float* bc1 = (const float*)d_in[10];
    const float* Wc2 = (const float*)d_in[11];
    const float* bc2 = (const float*)d_in[12];
    const int* src      = (const int*)d_in[13];
    const int* dst      = (const int*)d_in[14];
    const int* sidx     = (const int*)d_in[15];
    const int* lengths  = (const int*)d_in[16];
    float* out = (float*)d_out;

    char* ws = (char*)d_ws;
    size_t off = 0;
    auto alloc = [&](size_t bytes) -> void* {
        void* p = ws + off;
        off = (off + bytes + 255) & ~(size_t)255;
        return p;
    };
    unsigned short* in_bf  = (unsigned short*)alloc(2 * (size_t)N_NODES * EMB);
    unsigned short* agg_bf = (unsigned short*)alloc(2 * (size_t)N_NODES * EMB);
    unsigned short* h_bf   = (unsigned short*)alloc(2 * (size_t)N_NODES * EMB);
    unsigned short* hn_bf  = (unsigned short*)alloc(2 * (size_t)N_NODES * EMB);
    int*   row_ptr  = (int*)alloc(sizeof(int) * (N_NODES + 1));
    int*   cnt      = (int*)alloc(sizeof(int) * N_NODES);
    int*   blk      = (int*)alloc(sizeof(int) * SCAN_NB);
    int*   edge_src = (int*)alloc(sizeof(int) * N_EDGES);
    unsigned short* Wpk3 = (unsigned short*)alloc(2 * 8 * 12 * 8 * 512);  // 768 KB
    unsigned short* W1b  = (unsigned short*)alloc(2 * 128 * 128);
    unsigned short* W2b  = (unsigned short*)alloc(2 * 128 * 128);
    float* bsum     = (float*)alloc(sizeof(float) * 1024);
    float* hlast    = (float*)alloc(sizeof(float) * NSENT * LH);
    unsigned long long* hX = (unsigned long long*)alloc(2 * (size_t)NSENT * 64 * 8);  // 2 MB
    int* gcnt       = (int*)alloc(sizeof(int) * NGRP * 32);

    // weight prep (independent of everything else)
    k_prep<<<(1024 * 384 + 1024 + 32768 + 255) / 256, 256, 0, stream>>>(
        Wi, Wh, bi, bh, W1, W2, Wpk3, bsum, W1b, W2b);

    // LSTM exchange buffers: arrival counters = 0 (hX zeroed for hygiene)
    hipMemsetAsync(hX, 0, 2 * (size_t)NSENT * 64 * 8, stream);
    hipMemsetAsync(gcnt, 0, sizeof(int) * NGRP * 32, stream);

    // CSR build
    hipMemsetAsync(cnt, 0, sizeof(int) * N_NODES, stream);
    k_hist<<<(N_EDGES + 255) / 256, 256, 0, stream>>>(dst, cnt);
    k_scan_blk<<<SCAN_NB, 256, 0, stream>>>(cnt, row_ptr, blk);
    k_scan_tot<<<1, 256, 0, stream>>>(blk);
    k_scan_add<<<SCAN_NB, 256, 0, stream>>>(row_ptr, blk);
    hipMemsetAsync(cnt, 0, sizeof(int) * N_NODES, stream);
    k_scatter<<<(N_EDGES + 255) / 256, 256, 0, stream>>>(src, dst, row_ptr, cnt, edge_src);

    // GCN (bf16 path)
    k_tobf16<<<(N_NODES * EMB / 4 + 255) / 256, 256, 0, stream>>>(inputs, in_bf);
    k_aggregate_bf<<<(N_NODES * 64) / 256, 256, 0, stream>>>(in_bf, row_ptr, edge_src, agg_bf);
    k_gcn_mfma<<<(N_NODES + 63) / 64, 256, 0, stream>>>(agg_bf, W1b, b1, h_bf, N_NODES, 1);
    k_aggregate_bf<<<(N_NODES * 64) / 256, 256, 0, stream>>>(h_bf, row_ptr, edge_src, agg_bf);
    k_gcn_mfma<<<(N_NODES + 63) / 64, 256, 0, stream>>>(agg_bf, W2b, b2, hn_bf, N_NODES, 0);

    // LSTM: weight-stationary, 256 blocks = 8 u-slices x 32 groups, block-level sync
    k_lstm_ws8<<<NGRP * 8, 512, 0, stream>>>(hn_bf, Wpk3, bsum, sidx, lengths,
                                             hX, gcnt, hlast);

    // classifier
    k_classifier<<<NSENT / 4, 256, 0, stream>>>(hlast, Wc1, bc1, Wc2, bc2, out);
}

// Round 8
// 642.808 us; speedup vs baseline: 3.1767x; 1.0181x over previous
//
#include <hip/hip_runtime.h>
#include <hip/hip_bf16.h>
#include <math.h>

#define N_NODES 50000
#define N_EDGES 800000
#define EMB 128
#define LH 256
#define NSENT 2048
#define MAXLEN 32
#define SCAN_NB 196   // ceil(50000/256)
#define NG 64         // sentences per group
#define NGRP 32       // groups (NSENT/NG)

typedef __attribute__((ext_vector_type(8))) short short8;
typedef __attribute__((ext_vector_type(4))) float f32x4;

__device__ __forceinline__ unsigned short f2bf_u(float f) {
    __hip_bfloat16 h = __float2bfloat16(f);
    return *reinterpret_cast<unsigned short*>(&h);
}
__device__ __forceinline__ float bfu2f(unsigned short u) {
    unsigned int x = ((unsigned int)u) << 16;
    return __uint_as_float(x);
}

// fast activations: ~1e-7 abs error, negligible vs bf16 h-state rounding (2^-9)
__device__ __forceinline__ float fsig(float x) {
    return 1.f / (1.f + __expf(-x));
}
__device__ __forceinline__ float ftanh(float x) {
    return 1.f - 2.f / (__expf(2.f * x) + 1.f);
}

#define WAITVM0() __builtin_amdgcn_s_waitcnt(0xF70)   // vmcnt(0)

// async global->LDS, 16B/lane; gsrc per-lane, LDS dst = wave-uniform base + lane*16
__device__ __forceinline__ void gload_lds16(const void* gsrc, void* ldst) {
    __builtin_amdgcn_global_load_lds(
        (const __attribute__((address_space(1))) unsigned int*)gsrc,
        (__attribute__((address_space(3))) unsigned int*)ldst, 16, 0, 0);
}

// ---------------- CSR build ----------------

__global__ void k_hist(const int* __restrict__ dst, int* __restrict__ cnt) {
    int i = blockIdx.x * 256 + threadIdx.x;
    if (i < N_EDGES) atomicAdd(&cnt[dst[i]], 1);
}

__global__ void k_scan_blk(const int* __restrict__ cnt, int* __restrict__ row_ptr,
                           int* __restrict__ blk) {
    int b = blockIdx.x, t = threadIdx.x;
    int i = b * 256 + t;
    int lane = t & 63, wid = t >> 6;
    int v = (i < N_NODES) ? cnt[i] : 0;
    int x = v;
    #pragma unroll
    for (int off = 1; off < 64; off <<= 1) {
        int y = __shfl_up(x, off);
        if (lane >= off) x += y;
    }
    __shared__ int ws[4];
    if (lane == 63) ws[wid] = x;
    __syncthreads();
    if (t == 0) {
        int s = 0;
        #pragma unroll
        for (int j = 0; j < 4; j++) { int tmp = ws[j]; ws[j] = s; s += tmp; }
        blk[b] = s;
    }
    __syncthreads();
    if (i < N_NODES) row_ptr[i] = ws[wid] + x - v;
}

__global__ void k_scan_tot(int* __restrict__ blk) {
    int t = threadIdx.x;
    int lane = t & 63, wid = t >> 6;
    int v = (t < SCAN_NB) ? blk[t] : 0;
    int x = v;
    #pragma unroll
    for (int off = 1; off < 64; off <<= 1) {
        int y = __shfl_up(x, off);
        if (lane >= off) x += y;
    }
    __shared__ int ws[4];
    if (lane == 63) ws[wid] = x;
    __syncthreads();
    if (t == 0) {
        int s = 0;
        #pragma unroll
        for (int j = 0; j < 4; j++) { int tmp = ws[j]; ws[j] = s; s += tmp; }
    }
    __syncthreads();
    if (t < SCAN_NB) blk[t] = ws[wid] + x - v;
}

__global__ void k_scan_add(int* __restrict__ row_ptr, const int* __restrict__ blk) {
    int i = blockIdx.x * 256 + threadIdx.x;
    if (i < N_NODES) row_ptr[i] += blk[i >> 8];
    if (i == 0) row_ptr[N_NODES] = N_EDGES;
}

__global__ void k_scatter(const int* __restrict__ src, const int* __restrict__ dst,
                          const int* __restrict__ row_ptr, int* __restrict__ cnt,
                          int* __restrict__ edge_src) {
    int i = blockIdx.x * 256 + threadIdx.x;
    if (i < N_EDGES) {
        int d = dst[i];
        int pos = row_ptr[d] + atomicAdd(&cnt[d], 1);
        edge_src[pos] = src[i];
    }
}

// ---------------- fp32 -> bf16 convert (inputs) ----------------

__global__ void k_tobf16(const float* __restrict__ x, unsigned short* __restrict__ y) {
    int i = blockIdx.x * 256 + threadIdx.x;
    float4 v = ((const float4*)x)[i];
    ushort4 u;
    u.x = f2bf_u(v.x); u.y = f2bf_u(v.y); u.z = f2bf_u(v.z); u.w = f2bf_u(v.w);
    ((ushort4*)y)[i] = u;
}

// ---------------- aggregation: wave per node, 4 edge-slots x 16B/lane ----------------

__global__ void k_aggregate_bf(const unsigned short* __restrict__ feat,
                               const int* __restrict__ row_ptr,
                               const int* __restrict__ edge_src,
                               unsigned short* __restrict__ outb) {
    int w = (blockIdx.x * 256 + threadIdx.x) >> 6;
    int lane = threadIdx.x & 63;
    if (w >= N_NODES) return;
    int slot = lane >> 4, li = lane & 15;
    int beg = row_ptr[w], end = row_ptr[w + 1];
    float acc[8] = {};
    #pragma unroll 1
    for (int e = beg; e < end; e += 4) {
        int eidx = e + slot;
        if (eidx < end) {
            int s = edge_src[eidx];
            short8 v = *(const short8*)((const short*)feat + (size_t)s * EMB + li * 8);
            #pragma unroll
            for (int j = 0; j < 8; j++) acc[j] += bfu2f((unsigned short)v[j]);
        }
    }
    #pragma unroll
    for (int j = 0; j < 8; j++) {
        float t = acc[j];
        t += __shfl_xor(t, 16);
        t += __shfl_xor(t, 32);
        acc[j] = t;
    }
    if (slot == 0) {
        short8 o;
        #pragma unroll
        for (int j = 0; j < 8; j++) o[j] = (short)f2bf_u(acc[j]);
        *(short8*)((short*)outb + (size_t)w * EMB + li * 8) = o;
    }
}

// ---------------- GCN linear via MFMA ----------------

__global__ void __launch_bounds__(256)
k_gcn_mfma(const unsigned short* __restrict__ Ab,   // [M][128] bf16
           const unsigned short* __restrict__ Wb,   // [128][128] bf16
           const float* __restrict__ bias,
           unsigned short* __restrict__ outb,
           int M, int do_tanh) {
    int tid = threadIdx.x;
    int w = tid >> 6, lane = tid & 63;
    int l16 = lane & 15, quad = lane >> 4;
    int rbase = blockIdx.x * 64 + w * 16;
    int arow = rbase + l16;
    if (arow >= M) arow = M - 1;
    const short* Ap = (const short*)Ab + (size_t)arow * 128 + quad * 8;
    const short* Wp = (const short*)Wb;
    f32x4 acc[8] = {};
    #pragma unroll
    for (int ks = 0; ks < 4; ks++) {
        short8 a = *(const short8*)(Ap + ks * 32);
        #pragma unroll
        for (int ct = 0; ct < 8; ct++) {
            short8 b = *(const short8*)(Wp + (size_t)(ct * 16 + l16) * 128 + ks * 32 + quad * 8);
            acc[ct] = __builtin_amdgcn_mfma_f32_16x16x32_bf16(a, b, acc[ct], 0, 0, 0);
        }
    }
    #pragma unroll
    for (int ct = 0; ct < 8; ct++) {
        float bcol = bias[ct * 16 + l16];
        #pragma unroll
        for (int r = 0; r < 4; r++) {
            int row = rbase + quad * 4 + r;
            if (row < M) {
                float v = acc[ct][r] + bcol;
                if (do_tanh) v = tanhf(v);
                outb[(size_t)row * 128 + ct * 16 + l16] = f2bf_u(v);
            }
        }
    }
}

// ---------------- prep: Wpk3 (per-u-slice fragment-linear Wi|Wh) ----------------
// Block usl (0..7) owns h-cols u in [usl*32, usl*32+32) for ALL 4 gates ->
// 128 gate rows R = g*256 + usl*32 + u' over K=384 (k<128: Wi, k>=128: Wh) = 96 KB.
// Fragment (ks 0..11, ct = g*2 + (u'>>4)) at ((usl*12+ks)*8+ct)*512 shorts; element
// lane*8+jj = W[R(ct, l16=lane&15)][ks*32 + (lane>>4)*8 + jj].

__global__ void k_prep(const float* __restrict__ Wi, const float* __restrict__ Wh,
                       const float* __restrict__ bi, const float* __restrict__ bh,
                       const float* __restrict__ W1, const float* __restrict__ W2,
                       unsigned short* __restrict__ Wpk3, float* __restrict__ bsum,
                       unsigned short* __restrict__ W1b, unsigned short* __restrict__ W2b) {
    int idx = blockIdx.x * 256 + threadIdx.x;
    if (idx < 1024 * 384) {
        int R = idx / 384, k = idx - R * 384;
        float v = (k < 128) ? Wi[R * 128 + k] : Wh[R * 256 + (k - 128)];
        int g = R >> 8, u = R & 255;
        int usl = u >> 5, up = u & 31;
        int ct = g * 2 + (up >> 4);
        int l16v = up & 15;
        int ks = k >> 5, kk = k & 31;
        int quad = kk >> 3, jj = kk & 7;
        int lane = quad * 16 + l16v;
        Wpk3[(((size_t)usl * 12 + ks) * 8 + ct) * 512 + lane * 8 + jj] = f2bf_u(v);
    } else if (idx < 1024 * 384 + 1024) {
        int r = idx - 1024 * 384;
        bsum[r] = bi[r] + bh[r];
    } else if (idx < 1024 * 384 + 1024 + 16384) {
        int r = idx - (1024 * 384 + 1024);
        W1b[r] = f2bf_u(W1[r]);
    } else if (idx < 1024 * 384 + 1024 + 32768) {
        int r = idx - (1024 * 384 + 1024 + 16384);
        W2b[r] = f2bf_u(W2[r]);
    }
}

// ---------------- LSTM: weight-stationary IN REGISTERS, atomic h-exchange ------------
// R21: R7 = 324us, ~24K cyc/step. Accounting: MFMA 1.5K + VALU 3.4K + conflicts 1.9K
// + LDS port 4.6K (8 waves x 48 ds_read_b128) + ~12K serialized phase latency.
// Changes vs R7 (sync skeleton untouched -- R5/R7-proven):
// (a) B-weights -> REGISTERS permanently: each wave's 24 fragments (96 VGPR) loaded
//     once in the prologue (weights are time-invariant; only 8 waves/CU resident at
//     1 block/CU -> 256-VGPR budget/wave). Deletes wlds (96 KB LDS) and 24 of 48
//     ds_read_b128 per wave per step. amdgpu_waves_per_eu(2,2) makes the budget
//     explicit. Spill signature to watch: FETCH_SIZE explosion (R1-R3).
// (b) gl (gates) gets its OWN LDS region (freed by wlds removal) -> no alias with
//     xb/hb -> the post-GEMM WAR barrier (R7's B2) is deleted: 4 barriers/step.
// (c) bias folded into accumulator init (bias is per-column; MFMA D cols are
//     lane-indexed): removes 16 VALU adds/thread/step and the bs registers.

__global__ void __launch_bounds__(512)
__attribute__((amdgpu_waves_per_eu(2, 2)))
k_lstm_ws8(const unsigned short* __restrict__ hn_bf,   // [N_NODES][128] bf16
           const unsigned short* __restrict__ Wpk3,    // packed, see k_prep
           const float* __restrict__ bsum,             // [1024]
           const int* __restrict__ sidx,               // [NSENT][MAXLEN]
           const int* __restrict__ lengths,            // [NSENT]
           unsigned long long* __restrict__ hX,        // [2][NSENT][64] (256 bf16/row)
           int* __restrict__ gcnt,                     // [NGRP*32] arrival ctrs (memset 0)
           float* __restrict__ h_last) {               // [NSENT][256] fp32
    __shared__ unsigned short xb[64 * 128];            // 16 KB x_t (chunk-swizzled)
    __shared__ unsigned short hb[64 * 256];            // 32 KB h_t (chunk-swizzled)
    __shared__ float gl[64 * 132];                     // 33 KB gates (independent region)
    __shared__ int nid_sh[NG * 33];                    // 8448 B

    int tid = threadIdx.x;
    int w = tid >> 6, lane = tid & 63;
    int l16 = lane & 15, quad = lane >> 4;
    int usl = blockIdx.x >> 5;        // u-slice 0..7
    int grp = blockIdx.x & 31;        // sentence group 0..31 (same-XCD under %8 rr)
    int s0 = grp * NG;
    const short* hnp = (const short*)hn_bf;

    int m2 = w >> 2, cp4 = w & 3;     // GEMM wave grid: 2 m-groups x 4 col-groups (32x32)
    int row0 = m2 * 32 + l16, row1 = row0 + 16;

    // ---- prologue: this wave's 24 B-fragments -> REGISTERS (time-invariant) ----
    short8 breg[12][2];
    {
        const short* wsrc = (const short*)Wpk3 + (size_t)usl * 49152 + lane * 8;
        #pragma unroll
        for (int ks = 0; ks < 12; ks++)
            #pragma unroll
            for (int c = 0; c < 2; c++)
                breg[ks][c] = *(const short8*)(wsrc + (size_t)(ks * 8 + cp4 * 2 + c) * 512);
    }
    // bias for this wave's two 16-col tiles (folded into acc init each step)
    float bc0 = bsum[cp4 * 256 + usl * 32 + l16];
    float bc1 = bsum[cp4 * 256 + usl * 32 + 16 + l16];

    // x0 -> xb via async gload (pre-swizzled source)
    #pragma unroll
    for (int i = 0; i < 2; i++) {
        int row = w * 8 + i * 4 + quad;
        int nid = sidx[(size_t)(s0 + row) * MAXLEN + 0];
        int schunk = (l16 & ~7) | ((l16 ^ row) & 7);
        gload_lds16(hnp + (size_t)nid * 128 + schunk * 8,
                    (void*)((char*)xb + (size_t)(w * 8 + i * 4) * 256));
    }
    for (int i = tid; i < NG * 32; i += 512)
        nid_sh[(i >> 5) * 33 + (i & 31)] = sidx[(size_t)(s0 + (i >> 5)) * MAXLEN + (i & 31)];
    for (int i = tid; i < 64 * 128; i += 512) ((unsigned int*)hb)[i] = 0;  // h_{-1}=0

    // pointwise-thread constants: (psent = tid>>3, 4 h-cols u'0 = (tid&7)*4 ..)
    int psent = tid >> 3, j8 = tid & 7, u0 = j8 * 4;
    int len_reg = lengths[s0 + psent];
    float c_reg[4] = {};

    short8 xr[2];                     // x(t+1) register prefetch

    __syncthreads();                  // prologue staged (drains gload vmcnt)

    #pragma unroll 1
    for (int t = 0; t < MAXLEN; t++) {
        if (t > 0) {
            // ---- B0: tid0 acquire spin (all 8 blocks of group arrived t-1) ----
            if (tid == 0) {
                while (__hip_atomic_load(&gcnt[grp * 32], __ATOMIC_ACQUIRE,
                                         __HIP_MEMORY_SCOPE_AGENT) < 8 * t)
                    __builtin_amdgcn_s_sleep(1);
            }
            __syncthreads();
            // ---- x_t: ds_write prefetched regs ----
            {
                int row = tid >> 3;
                #pragma unroll
                for (int k = 0; k < 2; k++) {
                    int slot = j8 * 2 + k;
                    *(short8*)(xb + row * 128 + slot * 8) = xr[k];
                }
            }
            // ---- h_t: agent-scope atomic loads -> swizzled ds_write to hb ----
            {
                const unsigned long long* hr = hX + (size_t)(t & 1) * NSENT * 64
                                               + (size_t)(s0 + psent) * 64 + j8 * 8;
                unsigned long long hv[8];
                #pragma unroll
                for (int k = 0; k < 8; k++)
                    hv[k] = __hip_atomic_load(&hr[k], __ATOMIC_RELAXED,
                                              __HIP_MEMORY_SCOPE_AGENT);
                #pragma unroll
                for (int p = 0; p < 4; p++) {
                    int cc = j8 * 4 + p;
                    int slot = (cc & ~7) | ((cc ^ psent) & 7);
                    union { unsigned long long q[2]; short8 s; } uu;
                    uu.q[0] = hv[2 * p]; uu.q[1] = hv[2 * p + 1];
                    *(short8*)(hb + psent * 256 + slot * 8) = uu.s;
                }
            }
            __syncthreads();   // B1: staging visible to all waves
        }

        // ---- issue x(t+1) global->reg prefetch (hidden under GEMM) ----
        if (t + 1 < MAXLEN) {
            int row = tid >> 3;
            int nid = nid_sh[row * 33 + (t + 1)];
            #pragma unroll
            for (int k = 0; k < 2; k++) {
                int slot = j8 * 2 + k;
                int c = (slot & ~7) | ((slot ^ row) & 7);
                xr[k] = *(const short8*)(hnp + (size_t)nid * 128 + c * 8);
            }
        }

        // ---- GEMM: wave = rows [m2*32,+32) x cols [cp4*32,+32), K=384; B in regs ----
        f32x4 acc00 = {bc0, bc0, bc0, bc0};
        f32x4 acc01 = {bc1, bc1, bc1, bc1};
        f32x4 acc10 = {bc0, bc0, bc0, bc0};
        f32x4 acc11 = {bc1, bc1, bc1, bc1};
        #pragma unroll
        for (int ks = 0; ks < 12; ks++) {
            short8 a0, a1;
            if (ks < 4) {
                int kc = ks * 4 + quad;
                a0 = *(const short8*)(xb + row0 * 128 + (((kc & ~7) | ((kc ^ row0) & 7)) * 8));
                a1 = *(const short8*)(xb + row1 * 128 + (((kc & ~7) | ((kc ^ row1) & 7)) * 8));
            } else {
                int kc = (ks - 4) * 4 + quad;
                a0 = *(const short8*)(hb + row0 * 256 + (((kc & ~7) | ((kc ^ row0) & 7)) * 8));
                a1 = *(const short8*)(hb + row1 * 256 + (((kc & ~7) | ((kc ^ row1) & 7)) * 8));
            }
            acc00 = __builtin_amdgcn_mfma_f32_16x16x32_bf16(a0, breg[ks][0], acc00, 0, 0, 0);
            acc01 = __builtin_amdgcn_mfma_f32_16x16x32_bf16(a0, breg[ks][1], acc01, 0, 0, 0);
            acc10 = __builtin_amdgcn_mfma_f32_16x16x32_bf16(a1, breg[ks][0], acc10, 0, 0, 0);
            acc11 = __builtin_amdgcn_mfma_f32_16x16x32_bf16(a1, breg[ks][1], acc11, 0, 0, 0);
        }

        // ---- acc (pre-biased) -> gates f32 [64][132] (ncol = g*32+u', g = cp4) ----
        #pragma unroll
        for (int r = 0; r < 4; r++) {
            int se0 = m2 * 32 + quad * 4 + r;
            int se1 = se0 + 16;
            gl[se0 * 132 + cp4 * 32 + l16]      = acc00[r];
            gl[se0 * 132 + cp4 * 32 + 16 + l16] = acc01[r];
            gl[se1 * 132 + cp4 * 32 + l16]      = acc10[r];
            gl[se1 * 132 + cp4 * 32 + 16 + l16] = acc11[r];
        }
        __syncthreads();   // B3: gates ready

        // ---- pointwise c/h for (psent, u-cols usl*32+u0 .. +3) ----
        {
            float4 G[4];
            #pragma unroll
            for (int g = 0; g < 4; g++)
                G[g] = *(const float4*)&gl[psent * 132 + g * 32 + u0];
            float hv4[4];
            const float* Gp0 = (const float*)&G[0];
            const float* Gp1 = (const float*)&G[1];
            const float* Gp2 = (const float*)&G[2];
            const float* Gp3 = (const float*)&G[3];
            #pragma unroll
            for (int j = 0; j < 4; j++) {
                float i_ = fsig(Gp0[j]);
                float f_ = fsig(Gp1[j]);
                float g_ = ftanh(Gp2[j]);
                float o_ = fsig(Gp3[j]);
                float c = f_ * c_reg[j] + i_ * g_;
                c_reg[j] = c;
                hv4[j] = o_ * ftanh(c);
            }
            unsigned long long hq =
                  (unsigned long long)f2bf_u(hv4[0])
                | ((unsigned long long)f2bf_u(hv4[1]) << 16)
                | ((unsigned long long)f2bf_u(hv4[2]) << 32)
                | ((unsigned long long)f2bf_u(hv4[3]) << 48);
            unsigned long long* hw = hX + (size_t)((t + 1) & 1) * NSENT * 64
                                     + (size_t)(s0 + psent) * 64 + usl * 8 + j8;
            __hip_atomic_store(hw, hq, __ATOMIC_RELAXED, __HIP_MEMORY_SCOPE_AGENT);
            if (len_reg == t + 1) {
                float4 o4 = make_float4(hv4[0], hv4[1], hv4[2], hv4[3]);
                *(float4*)&h_last[(size_t)(s0 + psent) * 256 + usl * 32 + u0] = o4;
            }
        }

        // ---- B4 + arrive: all block stores ack'd, single release add ----
        if (t + 1 < MAXLEN) {
            WAITVM0();
            __syncthreads();
            if (tid == 0)
                __hip_atomic_fetch_add(&gcnt[grp * 32], 1, __ATOMIC_RELEASE,
                                       __HIP_MEMORY_SCOPE_AGENT);
        }
    }
}

// ---------------- classifier ----------------

__global__ void k_classifier(const float* __restrict__ h_last,
                             const float* __restrict__ Wc1, const float* __restrict__ bc1,
                             const float* __restrict__ Wc2, const float* __restrict__ bc2,
                             float* __restrict__ out) {
    int lane = threadIdx.x & 63;
    int wslot = threadIdx.x >> 6;
    int s = blockIdx.x * 4 + wslot;
    __shared__ float e_sh[4][256];
    const float* hr = h_last + (size_t)s * 256;
    #pragma unroll
    for (int i = 0; i < 4; i++) {
        float v = hr[lane + 64 * i];
        e_sh[wslot][lane + 64 * i] = fmaxf(v, 0.f);
    }
    __syncthreads();
    float zpart = 0.f;
    #pragma unroll
    for (int jj = 0; jj < 2; jj++) {
        int j = lane + 64 * jj;
        float a = bc1[j];
        const float4* wr = (const float4*)(Wc1 + (size_t)j * 256);
        #pragma unroll 8
        for (int k4 = 0; k4 < 64; k4++) {
            float4 wv = wr[k4];
            float4 e = *(const float4*)&e_sh[wslot][k4 * 4];
            a += wv.x * e.x + wv.y * e.y + wv.z * e.z + wv.w * e.w;
        }
        a = fmaxf(a, 0.f);
        zpart += a * Wc2[j];
    }
    #pragma unroll
    for (int off = 32; off > 0; off >>= 1) zpart += __shfl_down(zpart, off);
    if (lane == 0) out[s] = zpart + bc2[0];
}

// ---------------- launcher ----------------

extern "C" void kernel_launch(void* const* d_in, const int* in_sizes, int n_in,
                              void* d_out, int out_size, void* d_ws, size_t ws_size,
                              hipStream_t stream) {
    const float* inputs = (const float*)d_in[0];
    const float* W1  = (const float*)d_in[1];
    const float* b1  = (const float*)d_in[2];
    const float* W2  = (const float*)d_in[3];
    const float* b2  = (const float*)d_in[4];
    const float* Wi  = (const float*)d_in[5];
    const float* Wh  = (const float*)d_in[6];
    const float* bi  = (const float*)d_in[7];
    const float* bh  = (const float*)d_in[8];
    const float* Wc1 = (const float*)d_in[9];
    const float* bc1 = (const float*)d_in[10];
    const float* Wc2 = (const float*)d_in[11];
    const float* bc2 = (const float*)d_in[12];
    const int* src      = (const int*)d_in[13];
    const int* dst      = (const int*)d_in[14];
    const int* sidx     = (const int*)d_in[15];
    const int* lengths  = (const int*)d_in[16];
    float* out = (float*)d_out;

    char* ws = (char*)d_ws;
    size_t off = 0;
    auto alloc = [&](size_t bytes) -> void* {
        void* p = ws + off;
        off = (off + bytes + 255) & ~(size_t)255;
        return p;
    };
    unsigned short* in_bf  = (unsigned short*)alloc(2 * (size_t)N_NODES * EMB);
    unsigned short* agg_bf = (unsigned short*)alloc(2 * (size_t)N_NODES * EMB);
    unsigned short* h_bf   = (unsigned short*)alloc(2 * (size_t)N_NODES * EMB);
    unsigned short* hn_bf  = (unsigned short*)alloc(2 * (size_t)N_NODES * EMB);
    int*   row_ptr  = (int*)alloc(sizeof(int) * (N_NODES + 1));
    int*   cnt      = (int*)alloc(sizeof(int) * N_NODES);
    int*   blk      = (int*)alloc(sizeof(int) * SCAN_NB);
    int*   edge_src = (int*)alloc(sizeof(int) * N_EDGES);
    unsigned short* Wpk3 = (unsigned short*)alloc(2 * 8 * 12 * 8 * 512);  // 768 KB
    unsigned short* W1b  = (unsigned short*)alloc(2 * 128 * 128);
    unsigned short* W2b  = (unsigned short*)alloc(2 * 128 * 128);
    float* bsum     = (float*)alloc(sizeof(float) * 1024);
    float* hlast    = (float*)alloc(sizeof(float) * NSENT * LH);
    unsigned long long* hX = (unsigned long long*)alloc(2 * (size_t)NSENT * 64 * 8);  // 2 MB
    int* gcnt       = (int*)alloc(sizeof(int) * NGRP * 32);

    // weight prep (independent of everything else)
    k_prep<<<(1024 * 384 + 1024 + 32768 + 255) / 256, 256, 0, stream>>>(
        Wi, Wh, bi, bh, W1, W2, Wpk3, bsum, W1b, W2b);

    // LSTM exchange buffers: arrival counters = 0 (hX zeroed for hygiene)
    hipMemsetAsync(hX, 0, 2 * (size_t)NSENT * 64 * 8, stream);
    hipMemsetAsync(gcnt, 0, sizeof(int) * NGRP * 32, stream);

    // CSR build
    hipMemsetAsync(cnt, 0, sizeof(int) * N_NODES, stream);
    k_hist<<<(N_EDGES + 255) / 256, 256, 0, stream>>>(dst, cnt);
    k_scan_blk<<<SCAN_NB, 256, 0, stream>>>(cnt, row_ptr, blk);
    k_scan_tot<<<1, 256, 0, stream>>>(blk);
    k_scan_add<<<SCAN_NB, 256, 0, stream>>>(row_ptr, blk);
    hipMemsetAsync(cnt, 0, sizeof(int) * N_NODES, stream);
    k_scatter<<<(N_EDGES + 255) / 256, 256, 0, stream>>>(src, dst, row_ptr, cnt, edge_src);

    // GCN (bf16 path)
    k_tobf16<<<(N_NODES * EMB / 4 + 255) / 256, 256, 0, stream>>>(inputs, in_bf);
    k_aggregate_bf<<<(N_NODES * 64) / 256, 256, 0, stream>>>(in_bf, row_ptr, edge_src, agg_bf);
    k_gcn_mfma<<<(N_NODES + 63) / 64, 256, 0, stream>>>(agg_bf, W1b, b1, h_bf, N_NODES, 1);
    k_aggregate_bf<<<(N_NODES * 64) / 256, 256, 0, stream>>>(h_bf, row_ptr, edge_src, agg_bf);
    k_gcn_mfma<<<(N_NODES + 63) / 64, 256, 0, stream>>>(agg_bf, W2b, b2, hn_bf, N_NODES, 0);

    // LSTM: weight-stationary (B in VGPRs), 256 blocks = 8 u-slices x 32 groups
    k_lstm_ws8<<<NGRP * 8, 512, 0, stream>>>(hn_bf, Wpk3, bsum, sidx, lengths,
                                             hX, gcnt, hlast);

    // classifier
    k_classifier<<<NSENT / 4, 256, 0, stream>>>(hlast, Wc1, bc1, Wc2, bc2, out);
}

// Round 9
// 532.998 us; speedup vs baseline: 3.8312x; 1.2060x over previous
//
#include <hip/hip_runtime.h>
#include <hip/hip_bf16.h>
#include <math.h>

#define N_NODES 50000
#define N_EDGES 800000
#define EMB 128
#define LH 256
#define NSENT 2048
#define MAXLEN 32
#define SCAN_NB 196   // ceil(50000/256)
#define NG 64         // sentences per group
#define NGRP 32       // groups (NSENT/NG)

typedef __attribute__((ext_vector_type(8))) short short8;
typedef __attribute__((ext_vector_type(4))) float f32x4;

__device__ __forceinline__ unsigned short f2bf_u(float f) {
    __hip_bfloat16 h = __float2bfloat16(f);
    return *reinterpret_cast<unsigned short*>(&h);
}
__device__ __forceinline__ float bfu2f(unsigned short u) {
    unsigned int x = ((unsigned int)u) << 16;
    return __uint_as_float(x);
}

// fast activations: ~1e-7 abs error, negligible vs bf16 h-state rounding (2^-9)
__device__ __forceinline__ float fsig(float x) {
    return 1.f / (1.f + __expf(-x));
}
__device__ __forceinline__ float ftanh(float x) {
    return 1.f - 2.f / (__expf(2.f * x) + 1.f);
}

#define WAITVM0() __builtin_amdgcn_s_waitcnt(0xF70)   // vmcnt(0)

// async global->LDS, 16B/lane; gsrc per-lane, LDS dst = wave-uniform base + lane*16
__device__ __forceinline__ void gload_lds16(const void* gsrc, void* ldst) {
    __builtin_amdgcn_global_load_lds(
        (const __attribute__((address_space(1))) unsigned int*)gsrc,
        (__attribute__((address_space(3))) unsigned int*)ldst, 16, 0, 0);
}

// ---------------- CSR build ----------------

__global__ void k_hist(const int* __restrict__ dst, int* __restrict__ cnt) {
    int i = blockIdx.x * 256 + threadIdx.x;
    if (i < N_EDGES) atomicAdd(&cnt[dst[i]], 1);
}

__global__ void k_scan_blk(const int* __restrict__ cnt, int* __restrict__ row_ptr,
                           int* __restrict__ blk) {
    int b = blockIdx.x, t = threadIdx.x;
    int i = b * 256 + t;
    int lane = t & 63, wid = t >> 6;
    int v = (i < N_NODES) ? cnt[i] : 0;
    int x = v;
    #pragma unroll
    for (int off = 1; off < 64; off <<= 1) {
        int y = __shfl_up(x, off);
        if (lane >= off) x += y;
    }
    __shared__ int ws[4];
    if (lane == 63) ws[wid] = x;
    __syncthreads();
    if (t == 0) {
        int s = 0;
        #pragma unroll
        for (int j = 0; j < 4; j++) { int tmp = ws[j]; ws[j] = s; s += tmp; }
        blk[b] = s;
    }
    __syncthreads();
    if (i < N_NODES) row_ptr[i] = ws[wid] + x - v;
}

__global__ void k_scan_tot(int* __restrict__ blk) {
    int t = threadIdx.x;
    int lane = t & 63, wid = t >> 6;
    int v = (t < SCAN_NB) ? blk[t] : 0;
    int x = v;
    #pragma unroll
    for (int off = 1; off < 64; off <<= 1) {
        int y = __shfl_up(x, off);
        if (lane >= off) x += y;
    }
    __shared__ int ws[4];
    if (lane == 63) ws[wid] = x;
    __syncthreads();
    if (t == 0) {
        int s = 0;
        #pragma unroll
        for (int j = 0; j < 4; j++) { int tmp = ws[j]; ws[j] = s; s += tmp; }
    }
    __syncthreads();
    if (t < SCAN_NB) blk[t] = ws[wid] + x - v;
}

__global__ void k_scan_add(int* __restrict__ row_ptr, const int* __restrict__ blk) {
    int i = blockIdx.x * 256 + threadIdx.x;
    if (i < N_NODES) row_ptr[i] += blk[i >> 8];
    if (i == 0) row_ptr[N_NODES] = N_EDGES;
}

__global__ void k_scatter(const int* __restrict__ src, const int* __restrict__ dst,
                          const int* __restrict__ row_ptr, int* __restrict__ cnt,
                          int* __restrict__ edge_src) {
    int i = blockIdx.x * 256 + threadIdx.x;
    if (i < N_EDGES) {
        int d = dst[i];
        int pos = row_ptr[d] + atomicAdd(&cnt[d], 1);
        edge_src[pos] = src[i];
    }
}

// ---------------- fp32 -> bf16 convert (inputs) ----------------

__global__ void k_tobf16(const float* __restrict__ x, unsigned short* __restrict__ y) {
    int i = blockIdx.x * 256 + threadIdx.x;
    float4 v = ((const float4*)x)[i];
    ushort4 u;
    u.x = f2bf_u(v.x); u.y = f2bf_u(v.y); u.z = f2bf_u(v.z); u.w = f2bf_u(v.w);
    ((ushort4*)y)[i] = u;
}

// ---------------- aggregation: wave per node, 4 edge-slots x 16B/lane ----------------

__global__ void k_aggregate_bf(const unsigned short* __restrict__ feat,
                               const int* __restrict__ row_ptr,
                               const int* __restrict__ edge_src,
                               unsigned short* __restrict__ outb) {
    int w = (blockIdx.x * 256 + threadIdx.x) >> 6;
    int lane = threadIdx.x & 63;
    if (w >= N_NODES) return;
    int slot = lane >> 4, li = lane & 15;
    int beg = row_ptr[w], end = row_ptr[w + 1];
    float acc[8] = {};
    #pragma unroll 1
    for (int e = beg; e < end; e += 4) {
        int eidx = e + slot;
        if (eidx < end) {
            int s = edge_src[eidx];
            short8 v = *(const short8*)((const short*)feat + (size_t)s * EMB + li * 8);
            #pragma unroll
            for (int j = 0; j < 8; j++) acc[j] += bfu2f((unsigned short)v[j]);
        }
    }
    #pragma unroll
    for (int j = 0; j < 8; j++) {
        float t = acc[j];
        t += __shfl_xor(t, 16);
        t += __shfl_xor(t, 32);
        acc[j] = t;
    }
    if (slot == 0) {
        short8 o;
        #pragma unroll
        for (int j = 0; j < 8; j++) o[j] = (short)f2bf_u(acc[j]);
        *(short8*)((short*)outb + (size_t)w * EMB + li * 8) = o;
    }
}

// ---------------- GCN linear via MFMA ----------------

__global__ void __launch_bounds__(256)
k_gcn_mfma(const unsigned short* __restrict__ Ab,   // [M][128] bf16
           const unsigned short* __restrict__ Wb,   // [128][128] bf16
           const float* __restrict__ bias,
           unsigned short* __restrict__ outb,
           int M, int do_tanh) {
    int tid = threadIdx.x;
    int w = tid >> 6, lane = tid & 63;
    int l16 = lane & 15, quad = lane >> 4;
    int rbase = blockIdx.x * 64 + w * 16;
    int arow = rbase + l16;
    if (arow >= M) arow = M - 1;
    const short* Ap = (const short*)Ab + (size_t)arow * 128 + quad * 8;
    const short* Wp = (const short*)Wb;
    f32x4 acc[8] = {};
    #pragma unroll
    for (int ks = 0; ks < 4; ks++) {
        short8 a = *(const short8*)(Ap + ks * 32);
        #pragma unroll
        for (int ct = 0; ct < 8; ct++) {
            short8 b = *(const short8*)(Wp + (size_t)(ct * 16 + l16) * 128 + ks * 32 + quad * 8);
            acc[ct] = __builtin_amdgcn_mfma_f32_16x16x32_bf16(a, b, acc[ct], 0, 0, 0);
        }
    }
    #pragma unroll
    for (int ct = 0; ct < 8; ct++) {
        float bcol = bias[ct * 16 + l16];
        #pragma unroll
        for (int r = 0; r < 4; r++) {
            int row = rbase + quad * 4 + r;
            if (row < M) {
                float v = acc[ct][r] + bcol;
                if (do_tanh) v = tanhf(v);
                outb[(size_t)row * 128 + ct * 16 + l16] = f2bf_u(v);
            }
        }
    }
}

// ---------------- prep: Wpk3 (per-u-slice fragment-linear Wi|Wh) ----------------
// Block usl (0..7) owns h-cols u in [usl*32, usl*32+32) for ALL 4 gates ->
// 128 gate rows R = g*256 + usl*32 + u' over K=384 (k<128: Wi, k>=128: Wh) = 96 KB.
// Fragment (ks 0..11, ct = g*2 + (u'>>4)) at ((usl*12+ks)*8+ct)*512 shorts; element
// lane*8+jj = W[R(ct, l16=lane&15)][ks*32 + (lane>>4)*8 + jj].

__global__ void k_prep(const float* __restrict__ Wi, const float* __restrict__ Wh,
                       const float* __restrict__ bi, const float* __restrict__ bh,
                       const float* __restrict__ W1, const float* __restrict__ W2,
                       unsigned short* __restrict__ Wpk3, float* __restrict__ bsum,
                       unsigned short* __restrict__ W1b, unsigned short* __restrict__ W2b) {
    int idx = blockIdx.x * 256 + threadIdx.x;
    if (idx < 1024 * 384) {
        int R = idx / 384, k = idx - R * 384;
        float v = (k < 128) ? Wi[R * 128 + k] : Wh[R * 256 + (k - 128)];
        int g = R >> 8, u = R & 255;
        int usl = u >> 5, up = u & 31;
        int ct = g * 2 + (up >> 4);
        int l16v = up & 15;
        int ks = k >> 5, kk = k & 31;
        int quad = kk >> 3, jj = kk & 7;
        int lane = quad * 16 + l16v;
        Wpk3[(((size_t)usl * 12 + ks) * 8 + ct) * 512 + lane * 8 + jj] = f2bf_u(v);
    } else if (idx < 1024 * 384 + 1024) {
        int r = idx - 1024 * 384;
        bsum[r] = bi[r] + bh[r];
    } else if (idx < 1024 * 384 + 1024 + 16384) {
        int r = idx - (1024 * 384 + 1024);
        W1b[r] = f2bf_u(W1[r]);
    } else if (idx < 1024 * 384 + 1024 + 32768) {
        int r = idx - (1024 * 384 + 1024 + 16384);
        W2b[r] = f2bf_u(W2[r]);
    }
}

// ---------------- LSTM: weight-stationary in regs, RELAXED atomic exchange -----------
// R22 post-mortem: R8 (B-in-regs, -1 barrier) moved only 324->318us. MFMA+VALU+
// conflicts account for ~6.7K of ~23.5K cyc/step -- the ~70% residual is invariant
// to all compute cuts. Theory: the ACQUIRE spin load emits a cache INVALIDATE per
// poll iteration and the RELEASE fetch_add emits an L2 WRITEBACK per block-step
// (gfx9 memory-model lowering) -- R4's threadfence disaster in miniature, smuggled
// in through memory orders. FETCH 26.7MB ~= 2x logical cold reads fits repeated
// invalidation. Fix: RELAXED everywhere. This is safe here: all cross-block data
// (hX, gcnt) moves via agent-scope atomics executing at the device coherence point
// (cache-bypassing by construction); write ordering is vmcnt(0) (hX stores ACK'd
// at coherence point before counter add issues); read ordering is data dependence
// (hX loads issued only after the poll observes 8t). hn_bf/sidx/weights immutable.

__global__ void __launch_bounds__(512)
__attribute__((amdgpu_waves_per_eu(2, 2)))
k_lstm_ws8(const unsigned short* __restrict__ hn_bf,   // [N_NODES][128] bf16
           const unsigned short* __restrict__ Wpk3,    // packed, see k_prep
           const float* __restrict__ bsum,             // [1024]
           const int* __restrict__ sidx,               // [NSENT][MAXLEN]
           const int* __restrict__ lengths,            // [NSENT]
           unsigned long long* __restrict__ hX,        // [2][NSENT][64] (256 bf16/row)
           int* __restrict__ gcnt,                     // [NGRP*32] arrival ctrs (memset 0)
           float* __restrict__ h_last) {               // [NSENT][256] fp32
    __shared__ unsigned short xb[64 * 128];            // 16 KB x_t (chunk-swizzled)
    __shared__ unsigned short hb[64 * 256];            // 32 KB h_t (chunk-swizzled)
    __shared__ float gl[64 * 132];                     // 33 KB gates (independent region)
    __shared__ int nid_sh[NG * 33];                    // 8448 B

    int tid = threadIdx.x;
    int w = tid >> 6, lane = tid & 63;
    int l16 = lane & 15, quad = lane >> 4;
    int usl = blockIdx.x >> 5;        // u-slice 0..7
    int grp = blockIdx.x & 31;        // sentence group 0..31 (same-XCD under %8 rr)
    int s0 = grp * NG;
    const short* hnp = (const short*)hn_bf;

    int m2 = w >> 2, cp4 = w & 3;     // GEMM wave grid: 2 m-groups x 4 col-groups (32x32)
    int row0 = m2 * 32 + l16, row1 = row0 + 16;

    // ---- prologue: this wave's 24 B-fragments -> REGISTERS (time-invariant) ----
    short8 breg[12][2];
    {
        const short* wsrc = (const short*)Wpk3 + (size_t)usl * 49152 + lane * 8;
        #pragma unroll
        for (int ks = 0; ks < 12; ks++)
            #pragma unroll
            for (int c = 0; c < 2; c++)
                breg[ks][c] = *(const short8*)(wsrc + (size_t)(ks * 8 + cp4 * 2 + c) * 512);
    }
    // bias for this wave's two 16-col tiles (folded into acc init each step)
    float bc0 = bsum[cp4 * 256 + usl * 32 + l16];
    float bc1 = bsum[cp4 * 256 + usl * 32 + 16 + l16];

    // x0 -> xb via async gload (pre-swizzled source)
    #pragma unroll
    for (int i = 0; i < 2; i++) {
        int row = w * 8 + i * 4 + quad;
        int nid = sidx[(size_t)(s0 + row) * MAXLEN + 0];
        int schunk = (l16 & ~7) | ((l16 ^ row) & 7);
        gload_lds16(hnp + (size_t)nid * 128 + schunk * 8,
                    (void*)((char*)xb + (size_t)(w * 8 + i * 4) * 256));
    }
    for (int i = tid; i < NG * 32; i += 512)
        nid_sh[(i >> 5) * 33 + (i & 31)] = sidx[(size_t)(s0 + (i >> 5)) * MAXLEN + (i & 31)];
    for (int i = tid; i < 64 * 128; i += 512) ((unsigned int*)hb)[i] = 0;  // h_{-1}=0

    // pointwise-thread constants: (psent = tid>>3, 4 h-cols u'0 = (tid&7)*4 ..)
    int psent = tid >> 3, j8 = tid & 7, u0 = j8 * 4;
    int len_reg = lengths[s0 + psent];
    float c_reg[4] = {};

    short8 xr[2];                     // x(t+1) register prefetch

    __syncthreads();                  // prologue staged (drains gload vmcnt)

    #pragma unroll 1
    for (int t = 0; t < MAXLEN; t++) {
        if (t > 0) {
            // ---- B0: tid0 RELAXED spin (no per-poll cache maintenance) ----
            if (tid == 0) {
                while (__hip_atomic_load(&gcnt[grp * 32], __ATOMIC_RELAXED,
                                         __HIP_MEMORY_SCOPE_AGENT) < 8 * t)
                    __builtin_amdgcn_s_sleep(1);
            }
            __syncthreads();
            // ---- x_t: ds_write prefetched regs ----
            {
                int row = tid >> 3;
                #pragma unroll
                for (int k = 0; k < 2; k++) {
                    int slot = j8 * 2 + k;
                    *(short8*)(xb + row * 128 + slot * 8) = xr[k];
                }
            }
            // ---- h_t: agent-scope relaxed atomic loads -> swizzled ds_write ----
            {
                const unsigned long long* hr = hX + (size_t)(t & 1) * NSENT * 64
                                               + (size_t)(s0 + psent) * 64 + j8 * 8;
                unsigned long long hv[8];
                #pragma unroll
                for (int k = 0; k < 8; k++)
                    hv[k] = __hip_atomic_load(&hr[k], __ATOMIC_RELAXED,
                                              __HIP_MEMORY_SCOPE_AGENT);
                #pragma unroll
                for (int p = 0; p < 4; p++) {
                    int cc = j8 * 4 + p;
                    int slot = (cc & ~7) | ((cc ^ psent) & 7);
                    union { unsigned long long q[2]; short8 s; } uu;
                    uu.q[0] = hv[2 * p]; uu.q[1] = hv[2 * p + 1];
                    *(short8*)(hb + psent * 256 + slot * 8) = uu.s;
                }
            }
            __syncthreads();   // B1: staging visible to all waves
        }

        // ---- issue x(t+1) global->reg prefetch (hidden under GEMM) ----
        if (t + 1 < MAXLEN) {
            int row = tid >> 3;
            int nid = nid_sh[row * 33 + (t + 1)];
            #pragma unroll
            for (int k = 0; k < 2; k++) {
                int slot = j8 * 2 + k;
                int c = (slot & ~7) | ((slot ^ row) & 7);
                xr[k] = *(const short8*)(hnp + (size_t)nid * 128 + c * 8);
            }
        }

        // ---- GEMM: wave = rows [m2*32,+32) x cols [cp4*32,+32), K=384; B in regs ----
        f32x4 acc00 = {bc0, bc0, bc0, bc0};
        f32x4 acc01 = {bc1, bc1, bc1, bc1};
        f32x4 acc10 = {bc0, bc0, bc0, bc0};
        f32x4 acc11 = {bc1, bc1, bc1, bc1};
        #pragma unroll
        for (int ks = 0; ks < 12; ks++) {
            short8 a0, a1;
            if (ks < 4) {
                int kc = ks * 4 + quad;
                a0 = *(const short8*)(xb + row0 * 128 + (((kc & ~7) | ((kc ^ row0) & 7)) * 8));
                a1 = *(const short8*)(xb + row1 * 128 + (((kc & ~7) | ((kc ^ row1) & 7)) * 8));
            } else {
                int kc = (ks - 4) * 4 + quad;
                a0 = *(const short8*)(hb + row0 * 256 + (((kc & ~7) | ((kc ^ row0) & 7)) * 8));
                a1 = *(const short8*)(hb + row1 * 256 + (((kc & ~7) | ((kc ^ row1) & 7)) * 8));
            }
            acc00 = __builtin_amdgcn_mfma_f32_16x16x32_bf16(a0, breg[ks][0], acc00, 0, 0, 0);
            acc01 = __builtin_amdgcn_mfma_f32_16x16x32_bf16(a0, breg[ks][1], acc01, 0, 0, 0);
            acc10 = __builtin_amdgcn_mfma_f32_16x16x32_bf16(a1, breg[ks][0], acc10, 0, 0, 0);
            acc11 = __builtin_amdgcn_mfma_f32_16x16x32_bf16(a1, breg[ks][1], acc11, 0, 0, 0);
        }

        // ---- acc (pre-biased) -> gates f32 [64][132] (ncol = g*32+u', g = cp4) ----
        #pragma unroll
        for (int r = 0; r < 4; r++) {
            int se0 = m2 * 32 + quad * 4 + r;
            int se1 = se0 + 16;
            gl[se0 * 132 + cp4 * 32 + l16]      = acc00[r];
            gl[se0 * 132 + cp4 * 32 + 16 + l16] = acc01[r];
            gl[se1 * 132 + cp4 * 32 + l16]      = acc10[r];
            gl[se1 * 132 + cp4 * 32 + 16 + l16] = acc11[r];
        }
        __syncthreads();   // B3: gates ready

        // ---- pointwise c/h for (psent, u-cols usl*32+u0 .. +3) ----
        {
            float4 G[4];
            #pragma unroll
            for (int g = 0; g < 4; g++)
                G[g] = *(const float4*)&gl[psent * 132 + g * 32 + u0];
            float hv4[4];
            const float* Gp0 = (const float*)&G[0];
            const float* Gp1 = (const float*)&G[1];
            const float* Gp2 = (const float*)&G[2];
            const float* Gp3 = (const float*)&G[3];
            #pragma unroll
            for (int j = 0; j < 4; j++) {
                float i_ = fsig(Gp0[j]);
                float f_ = fsig(Gp1[j]);
                float g_ = ftanh(Gp2[j]);
                float o_ = fsig(Gp3[j]);
                float c = f_ * c_reg[j] + i_ * g_;
                c_reg[j] = c;
                hv4[j] = o_ * ftanh(c);
            }
            unsigned long long hq =
                  (unsigned long long)f2bf_u(hv4[0])
                | ((unsigned long long)f2bf_u(hv4[1]) << 16)
                | ((unsigned long long)f2bf_u(hv4[2]) << 32)
                | ((unsigned long long)f2bf_u(hv4[3]) << 48);
            unsigned long long* hw = hX + (size_t)((t + 1) & 1) * NSENT * 64
                                     + (size_t)(s0 + psent) * 64 + usl * 8 + j8;
            __hip_atomic_store(hw, hq, __ATOMIC_RELAXED, __HIP_MEMORY_SCOPE_AGENT);
            if (len_reg == t + 1) {
                float4 o4 = make_float4(hv4[0], hv4[1], hv4[2], hv4[3]);
                *(float4*)&h_last[(size_t)(s0 + psent) * 256 + usl * 32 + u0] = o4;
            }
        }

        // ---- B4 + arrive: hX stores ACK'd at coherence point, RELAXED add ----
        if (t + 1 < MAXLEN) {
            WAITVM0();
            __syncthreads();
            if (tid == 0)
                __hip_atomic_fetch_add(&gcnt[grp * 32], 1, __ATOMIC_RELAXED,
                                       __HIP_MEMORY_SCOPE_AGENT);
        }
    }
}

// ---------------- classifier ----------------

__global__ void k_classifier(const float* __restrict__ h_last,
                             const float* __restrict__ Wc1, const float* __restrict__ bc1,
                             const float* __restrict__ Wc2, const float* __restrict__ bc2,
                             float* __restrict__ out) {
    int lane = threadIdx.x & 63;
    int wslot = threadIdx.x >> 6;
    int s = blockIdx.x * 4 + wslot;
    __shared__ float e_sh[4][256];
    const float* hr = h_last + (size_t)s * 256;
    #pragma unroll
    for (int i = 0; i < 4; i++) {
        float v = hr[lane + 64 * i];
        e_sh[wslot][lane + 64 * i] = fmaxf(v, 0.f);
    }
    __syncthreads();
    float zpart = 0.f;
    #pragma unroll
    for (int jj = 0; jj < 2; jj++) {
        int j = lane + 64 * jj;
        float a = bc1[j];
        const float4* wr = (const float4*)(Wc1 + (size_t)j * 256);
        #pragma unroll 8
        for (int k4 = 0; k4 < 64; k4++) {
            float4 wv = wr[k4];
            float4 e = *(const float4*)&e_sh[wslot][k4 * 4];
            a += wv.x * e.x + wv.y * e.y + wv.z * e.z + wv.w * e.w;
        }
        a = fmaxf(a, 0.f);
        zpart += a * Wc2[j];
    }
    #pragma unroll
    for (int off = 32; off > 0; off >>= 1) zpart += __shfl_down(zpart, off);
    if (lane == 0) out[s] = zpart + bc2[0];
}

// ---------------- launcher ----------------

extern "C" void kernel_launch(void* const* d_in, const int* in_sizes, int n_in,
                              void* d_out, int out_size, void* d_ws, size_t ws_size,
                              hipStream_t stream) {
    const float* inputs = (const float*)d_in[0];
    const float* W1  = (const float*)d_in[1];
    const float* b1  = (const float*)d_in[2];
    const float* W2  = (const float*)d_in[3];
    const float* b2  = (const float*)d_in[4];
    const float* Wi  = (const float*)d_in[5];
    const float* Wh  = (const float*)d_in[6];
    const float* bi  = (const float*)d_in[7];
    const float* bh  = (const float*)d_in[8];
    const float* Wc1 = (const float*)d_in[9];
    const float* bc1 = (const float*)d_in[10];
    const float* Wc2 = (const float*)d_in[11];
    const float* bc2 = (const float*)d_in[12];
    const int* src      = (const int*)d_in[13];
    const int* dst      = (const int*)d_in[14];
    const int* sidx     = (const int*)d_in[15];
    const int* lengths  = (const int*)d_in[16];
    float* out = (float*)d_out;

    char* ws = (char*)d_ws;
    size_t off = 0;
    auto alloc = [&](size_t bytes) -> void* {
        void* p = ws + off;
        off = (off + bytes + 255) & ~(size_t)255;
        return p;
    };
    unsigned short* in_bf  = (unsigned short*)alloc(2 * (size_t)N_NODES * EMB);
    unsigned short* agg_bf = (unsigned short*)alloc(2 * (size_t)N_NODES * EMB);
    unsigned short* h_bf   = (unsigned short*)alloc(2 * (size_t)N_NODES * EMB);
    unsigned short* hn_bf  = (unsigned short*)alloc(2 * (size_t)N_NODES * EMB);
    int*   row_ptr  = (int*)alloc(sizeof(int) * (N_NODES + 1));
    int*   cnt      = (int*)alloc(sizeof(int) * N_NODES);
    int*   blk      = (int*)alloc(sizeof(int) * SCAN_NB);
    int*   edge_src = (int*)alloc(sizeof(int) * N_EDGES);
    unsigned short* Wpk3 = (unsigned short*)alloc(2 * 8 * 12 * 8 * 512);  // 768 KB
    unsigned short* W1b  = (unsigned short*)alloc(2 * 128 * 128);
    unsigned short* W2b  = (unsigned short*)alloc(2 * 128 * 128);
    float* bsum     = (float*)alloc(sizeof(float) * 1024);
    float* hlast    = (float*)alloc(sizeof(float) * NSENT * LH);
    unsigned long long* hX = (unsigned long long*)alloc(2 * (size_t)NSENT * 64 * 8);  // 2 MB
    int* gcnt       = (int*)alloc(sizeof(int) * NGRP * 32);

    // weight prep (independent of everything else)
    k_prep<<<(1024 * 384 + 1024 + 32768 + 255) / 256, 256, 0, stream>>>(
        Wi, Wh, bi, bh, W1, W2, Wpk3, bsum, W1b, W2b);

    // LSTM exchange buffers: arrival counters = 0 (hX zeroed for hygiene)
    hipMemsetAsync(hX, 0, 2 * (size_t)NSENT * 64 * 8, stream);
    hipMemsetAsync(gcnt, 0, sizeof(int) * NGRP * 32, stream);

    // CSR build
    hipMemsetAsync(cnt, 0, sizeof(int) * N_NODES, stream);
    k_hist<<<(N_EDGES + 255) / 256, 256, 0, stream>>>(dst, cnt);
    k_scan_blk<<<SCAN_NB, 256, 0, stream>>>(cnt, row_ptr, blk);
    k_scan_tot<<<1, 256, 0, stream>>>(blk);
    k_scan_add<<<SCAN_NB, 256, 0, stream>>>(row_ptr, blk);
    hipMemsetAsync(cnt, 0, sizeof(int) * N_NODES, stream);
    k_scatter<<<(N_EDGES + 255) / 256, 256, 0, stream>>>(src, dst, row_ptr, cnt, edge_src);

    // GCN (bf16 path)
    k_tobf16<<<(N_NODES * EMB / 4 + 255) / 256, 256, 0, stream>>>(inputs, in_bf);
    k_aggregate_bf<<<(N_NODES * 64) / 256, 256, 0, stream>>>(in_bf, row_ptr, edge_src, agg_bf);
    k_gcn_mfma<<<(N_NODES + 63) / 64, 256, 0, stream>>>(agg_bf, W1b, b1, h_bf, N_NODES, 1);
    k_aggregate_bf<<<(N_NODES * 64) / 256, 256, 0, stream>>>(h_bf, row_ptr, edge_src, agg_bf);
    k_gcn_mfma<<<(N_NODES + 63) / 64, 256, 0, stream>>>(agg_bf, W2b, b2, hn_bf, N_NODES, 0);

    // LSTM: weight-stationary (B in VGPRs), relaxed atomic exchange
    k_lstm_ws8<<<NGRP * 8, 512, 0, stream>>>(hn_bf, Wpk3, bsum, sidx, lengths,
                                             hX, gcnt, hlast);

    // classifier
    k_classifier<<<NSENT / 4, 256, 0, stream>>>(hlast, Wc1, bc1, Wc2, bc2, out);
}